// Round 1
// baseline (1208.266 us; speedup 1.0000x reference)
//
#include <hip/hip_runtime.h>
#include <hip/hip_bf16.h>
#include <cstdint>

// Problem constants
#define NN   4
#define LL   4096      // 64*64
#define DD   18
#define CVV  128
#define CIN  256
#define CUU  10
#define HPW  64
#define HH   129
#define COO  10

// workspace layout (float offsets). val_t aliases p; ctx aliases val_pre; out_pre aliases u.
#define P_OFF    ((size_t)0)          // 4*256*4096 = 4194304   (later reused as val_t: 2097152)
#define U_OFF    ((size_t)4194304)    // 4*10*4096  = 163840    (later reused as out_pre)
#define Q_OFF    ((size_t)4358144)    // 4*4096*18  = 294912
#define K_OFF    ((size_t)4653056)    // 4*18*4096  = 294912
#define VP_OFF   ((size_t)4947968)    // 4*128*4096 = 2097152   (later reused as ctx)
#define VSC_OFF  ((size_t)7045120)    // 128
#define VSH_OFF  ((size_t)7045248)    // 128
#define S2_OFF   ((size_t)7045376)    // 16
#define SH2_OFF  ((size_t)7045392)    // 16
// total ~7045408 floats = 28.2 MB

// ---------------- avg pool 3x3 stride 2, VALID ----------------
__global__ __launch_bounds__(256) void pool_kernel(const float* __restrict__ src,
                                                   float* __restrict__ dst, int total) {
    int idx = blockIdx.x * 256 + threadIdx.x;
    if (idx >= total) return;
    int ow = idx & 63;
    int oh = (idx >> 6) & 63;
    int nc = idx >> 12;                       // n*C + c (layouts contiguous)
    const float* s = src + (size_t)nc * (HH * HH) + (size_t)(2 * oh) * HH + 2 * ow;
    float sum = s[0] + s[1] + s[2]
              + s[HH] + s[HH + 1] + s[HH + 2]
              + s[2 * HH] + s[2 * HH + 1] + s[2 * HH + 2];
    dst[idx] = sum * (1.0f / 9.0f);
}

// ---------------- query + key 1x1 convs with coord features ----------------
__global__ __launch_bounds__(256) void qk_kernel(const float* __restrict__ p,
                                                 const float* __restrict__ u,
                                                 const float* __restrict__ Wq,
                                                 const float* __restrict__ Wk,
                                                 float* __restrict__ q,
                                                 float* __restrict__ k) {
    int idx = blockIdx.x * 256 + threadIdx.x;   // over NN*LL
    int n = idx >> 12;
    int m = idx & 4095;
    int hi = m >> 6, wi = m & 63;

    float coord[8];
    coord[0] = wi * (2.0f / 64.0f) - 1.0f;
    coord[1] = hi * (2.0f / 64.0f) - 1.0f;
    coord[2] = (wi + 1) * (2.0f / 64.0f) - 1.0f;
    coord[3] = (hi + 1) * (2.0f / 64.0f) - 1.0f;
    coord[4] = 0.5f * (coord[0] + coord[2]);
    coord[5] = 0.5f * (coord[1] + coord[3]);
    coord[6] = 1.0f / 64.0f;
    coord[7] = 1.0f / 64.0f;

    // query = [u(10), coord(8)] @ Wq[18][18]
    {
        float acc[DD];
        #pragma unroll
        for (int o = 0; o < DD; ++o) acc[o] = 0.0f;
        for (int c = 0; c < CUU; ++c) {
            float uv = u[((size_t)(n * CUU + c)) * LL + m];
            #pragma unroll
            for (int o = 0; o < DD; ++o) acc[o] = fmaf(uv, Wq[o * DD + c], acc[o]);
        }
        #pragma unroll
        for (int j = 0; j < 8; ++j) {
            float cv = coord[j];
            #pragma unroll
            for (int o = 0; o < DD; ++o) acc[o] = fmaf(cv, Wq[o * DD + CUU + j], acc[o]);
        }
        #pragma unroll
        for (int o = 0; o < DD; ++o)
            q[((size_t)n * LL + m) * DD + o] = acc[o];
    }
    // key = [p(256), coord(8)] @ Wk[18][264]
    {
        float acc[DD];
        #pragma unroll
        for (int o = 0; o < DD; ++o) acc[o] = 0.0f;
        for (int c = 0; c < CIN; ++c) {
            float pv = p[((size_t)(n * CIN + c)) * LL + m];
            #pragma unroll
            for (int o = 0; o < DD; ++o) acc[o] = fmaf(pv, Wk[o * 264 + c], acc[o]);
        }
        #pragma unroll
        for (int j = 0; j < 8; ++j) {
            float cv = coord[j];
            #pragma unroll
            for (int o = 0; o < DD; ++o) acc[o] = fmaf(cv, Wk[o * 264 + CIN + j], acc[o]);
        }
        #pragma unroll
        for (int o = 0; o < DD; ++o)
            k[((size_t)(n * DD + o)) * LL + m] = acc[o];
    }
}

// ---------------- val pre-BN GEMM: val_pre[n][ch][m] = Wv[ch][:] . p[n][:][m] ----------------
__global__ __launch_bounds__(256) void val_gemm_kernel(const float* __restrict__ p,
                                                       const float* __restrict__ Wv,
                                                       float* __restrict__ val_pre) {
    // grid: 4 n * 8 chb * 16 mb = 512 blocks
    int b = blockIdx.x;
    int n = b >> 7;
    int r = b & 127;
    int chb = r >> 4;        // 0..7 -> 16 channels
    int mb = r & 15;
    int m = mb * 256 + threadIdx.x;
    int ch0 = chb * 16;

    float acc[16];
    #pragma unroll
    for (int i = 0; i < 16; ++i) acc[i] = 0.0f;

    for (int c = 0; c < CIN; ++c) {
        float pv = p[((size_t)(n * CIN + c)) * LL + m];
        #pragma unroll
        for (int i = 0; i < 16; ++i)
            acc[i] = fmaf(pv, Wv[(ch0 + i) * CIN + c], acc[i]);
    }
    #pragma unroll
    for (int i = 0; i < 16; ++i)
        val_pre[((size_t)(n * CVV + ch0 + i)) * LL + m] = acc[i];
}

// ---------------- BN stats over (N, L) per channel; fold gamma/beta ----------------
__global__ __launch_bounds__(256) void bn_stats_kernel(const float* __restrict__ src,
                                                       const float* __restrict__ g,
                                                       const float* __restrict__ bta,
                                                       float* __restrict__ scale,
                                                       float* __restrict__ shift,
                                                       int C) {
    int ch = blockIdx.x;
    float s = 0.0f, s2 = 0.0f;
    for (int i = threadIdx.x; i < NN * LL; i += 256) {
        int n = i >> 12;
        int m = i & 4095;
        float v = src[((size_t)(n * C + ch)) * LL + m];
        s += v;
        s2 = fmaf(v, v, s2);
    }
    __shared__ float rs[4], rs2[4];
    #pragma unroll
    for (int off = 32; off; off >>= 1) {
        s += __shfl_down(s, off);
        s2 += __shfl_down(s2, off);
    }
    int wid = threadIdx.x >> 6;
    if ((threadIdx.x & 63) == 0) { rs[wid] = s; rs2[wid] = s2; }
    __syncthreads();
    if (threadIdx.x == 0) {
        s = rs[0] + rs[1] + rs[2] + rs[3];
        s2 = rs2[0] + rs2[1] + rs2[2] + rs2[3];
        float mean = s * (1.0f / (NN * LL));
        float var = s2 * (1.0f / (NN * LL)) - mean * mean;
        float inv = rsqrtf(var + 1e-5f);
        float sc = g[ch] * inv;
        scale[ch] = sc;
        shift[ch] = bta[ch] - mean * sc;
    }
}

// ---------------- apply BN + relu, write transposed val_t[n][m][ch] ----------------
__global__ __launch_bounds__(256) void bn_apply_kernel(const float* __restrict__ val_pre,
                                                       const float* __restrict__ scale,
                                                       const float* __restrict__ shift,
                                                       float* __restrict__ val_t) {
    int t = blockIdx.x * 256 + threadIdx.x;   // over NN*LL*CVV
    int ch = t & 127;
    int r = t >> 7;
    int m = r & 4095;
    int n = r >> 12;
    float v = val_pre[((size_t)(n * CVV + ch)) * LL + m];
    v = fmaf(v, scale[ch], shift[ch]);
    val_t[((size_t)(n * LL + m)) * CVV + ch] = fmaxf(v, 0.0f);
}

// ---------------- fused attention: softmax(QK^T) @ V^T ----------------
__global__ __launch_bounds__(256) void attn_kernel(const float* __restrict__ q,
                                                   const float* __restrict__ k,
                                                   const float* __restrict__ vt,
                                                   float* __restrict__ ctx) {
    const int BL = 16, BM = 64;
    int b = blockIdx.x;       // 0..1023
    int n = b >> 8;
    int l0 = (b & 255) * BL;
    int tid = threadIdx.x;

    __shared__ float qs[BL][DD];
    __shared__ float Ms[BL], Sinv[BL];
    __shared__ float As[BL][BM];
    __shared__ __align__(16) float Vs[BM][CVV];    // 32 KB
    __shared__ float redm[4][BL], reds[4][BL];

    for (int i = tid; i < BL * DD; i += 256) {
        int l = i / DD, o = i % DD;
        qs[l][o] = q[((size_t)n * LL + l0 + l) * DD + o];
    }
    __syncthreads();

    // ---- pass 1: row max & exp-sum (per-thread online, then combine) ----
    float pmax[BL], psum[BL];
    #pragma unroll
    for (int l = 0; l < BL; ++l) { pmax[l] = -3.0e38f; psum[l] = 0.0f; }

    for (int it = 0; it < LL / 256; ++it) {
        int m = it * 256 + tid;
        float kr[DD];
        #pragma unroll
        for (int o = 0; o < DD; ++o) kr[o] = k[((size_t)(n * DD + o)) * LL + m];
        #pragma unroll
        for (int l = 0; l < BL; ++l) {
            float e = 0.0f;
            #pragma unroll
            for (int o = 0; o < DD; ++o) e = fmaf(qs[l][o], kr[o], e);
            if (e <= pmax[l]) {
                psum[l] += __expf(e - pmax[l]);
            } else {
                psum[l] = fmaf(psum[l], __expf(pmax[l] - e), 1.0f);
                pmax[l] = e;
            }
        }
    }
    int wid = tid >> 6, lane = tid & 63;
    #pragma unroll
    for (int l = 0; l < BL; ++l) {
        float m_ = pmax[l], s_ = psum[l];
        #pragma unroll
        for (int off = 32; off; off >>= 1) {
            float om = __shfl_xor(m_, off);
            float os = __shfl_xor(s_, off);
            float nm = fmaxf(m_, om);
            s_ = s_ * __expf(m_ - nm) + os * __expf(om - nm);
            m_ = nm;
        }
        if (lane == 0) { redm[wid][l] = m_; reds[wid][l] = s_; }
    }
    __syncthreads();
    if (tid < BL) {
        float m_ = redm[0][tid], s_ = reds[0][tid];
        #pragma unroll
        for (int w = 1; w < 4; ++w) {
            float om = redm[w][tid], os = reds[w][tid];
            float nm = fmaxf(m_, om);
            s_ = s_ * __expf(m_ - nm) + os * __expf(om - nm);
            m_ = nm;
        }
        Ms[tid] = m_;
        Sinv[tid] = 1.0f / s_;
    }

    // ---- pass 2: tile over m, recompute attn, accumulate PV ----
    int mloc = tid & 63;          // A-compute role
    int lq = tid >> 6;            // 0..3 (A-compute l group / FMA m split)
    int cg = tid & 15;            // c block: 8 channels
    int lg = (tid >> 4) & 3;      // l block: 4 rows
    int mq = tid >> 6;            // m interleave 0..3

    float acc[4][8];
    #pragma unroll
    for (int j = 0; j < 4; ++j)
        #pragma unroll
        for (int i2 = 0; i2 < 8; ++i2) acc[j][i2] = 0.0f;

    for (int mt = 0; mt < LL / BM; ++mt) {
        int m0 = mt * BM;
        __syncthreads();
        // stage V tile
        for (int i = tid; i < BM * CVV; i += 256) {
            int mm = i >> 7, cc = i & 127;
            Vs[mm][cc] = vt[((size_t)(n * LL + m0 + mm)) * CVV + cc];
        }
        // attn tile
        {
            float kr[DD];
            #pragma unroll
            for (int o = 0; o < DD; ++o)
                kr[o] = k[((size_t)(n * DD + o)) * LL + m0 + mloc];
            #pragma unroll
            for (int j = 0; j < 4; ++j) {
                int l = lq * 4 + j;
                float e = 0.0f;
                #pragma unroll
                for (int o = 0; o < DD; ++o) e = fmaf(qs[l][o], kr[o], e);
                As[l][mloc] = __expf(e - Ms[l]) * Sinv[l];
            }
        }
        __syncthreads();
        // PV FMA: each thread: 4 l x 8 c, m strided by 4
        #pragma unroll 4
        for (int i = 0; i < 16; ++i) {
            int mm = 4 * i + mq;
            float4 v0 = *(const float4*)&Vs[mm][cg * 8];
            float4 v1 = *(const float4*)&Vs[mm][cg * 8 + 4];
            #pragma unroll
            for (int j = 0; j < 4; ++j) {
                float a = As[lg * 4 + j][mm];
                acc[j][0] = fmaf(a, v0.x, acc[j][0]);
                acc[j][1] = fmaf(a, v0.y, acc[j][1]);
                acc[j][2] = fmaf(a, v0.z, acc[j][2]);
                acc[j][3] = fmaf(a, v0.w, acc[j][3]);
                acc[j][4] = fmaf(a, v1.x, acc[j][4]);
                acc[j][5] = fmaf(a, v1.y, acc[j][5]);
                acc[j][6] = fmaf(a, v1.z, acc[j][6]);
                acc[j][7] = fmaf(a, v1.w, acc[j][7]);
            }
        }
    }

    // ---- combine the 4-way m split, write ctx[n][l][c] ----
    __syncthreads();
    float* scr = (float*)Vs;      // 8192 floats of scratch
    int sslot = tid & 63;
    if (mq >= 2) {
        #pragma unroll
        for (int j = 0; j < 4; ++j)
            #pragma unroll
            for (int i2 = 0; i2 < 8; ++i2)
                scr[(((mq - 2) * 64 + sslot) * 32) + j * 8 + i2] = acc[j][i2];
    }
    __syncthreads();
    if (mq < 2) {
        #pragma unroll
        for (int j = 0; j < 4; ++j)
            #pragma unroll
            for (int i2 = 0; i2 < 8; ++i2)
                acc[j][i2] += scr[((mq * 64 + sslot) * 32) + j * 8 + i2];
    }
    __syncthreads();
    if (mq == 1) {
        #pragma unroll
        for (int j = 0; j < 4; ++j)
            #pragma unroll
            for (int i2 = 0; i2 < 8; ++i2)
                scr[(sslot * 32) + j * 8 + i2] = acc[j][i2];
    }
    __syncthreads();
    if (mq == 0) {
        #pragma unroll
        for (int j = 0; j < 4; ++j) {
            #pragma unroll
            for (int i2 = 0; i2 < 8; ++i2)
                acc[j][i2] += scr[(sslot * 32) + j * 8 + i2];
            size_t row = ((size_t)(n * LL + l0 + lg * 4 + j)) * CVV + cg * 8;
            *(float4*)&ctx[row]     = make_float4(acc[j][0], acc[j][1], acc[j][2], acc[j][3]);
            *(float4*)&ctx[row + 4] = make_float4(acc[j][4], acc[j][5], acc[j][6], acc[j][7]);
        }
    }
}

// ---------------- projection: out_pre[n][o][l] = Wp[o][:] . ctx[n][l][:] ----------------
__global__ __launch_bounds__(256) void proj_kernel(const float* __restrict__ ctx,
                                                   const float* __restrict__ Wp,
                                                   float* __restrict__ out_pre) {
    int idx = blockIdx.x * 256 + threadIdx.x;   // over NN*LL
    int n = idx >> 12;
    int l = idx & 4095;
    const float4* r4 = (const float4*)(ctx + ((size_t)(n * LL + l)) * CVV);
    float acc[COO];
    #pragma unroll
    for (int o = 0; o < COO; ++o) acc[o] = 0.0f;
    for (int c4 = 0; c4 < CVV / 4; ++c4) {
        float4 v = r4[c4];
        #pragma unroll
        for (int o = 0; o < COO; ++o) {
            const float* wr = Wp + o * CVV + c4 * 4;
            acc[o] = fmaf(v.x, wr[0], acc[o]);
            acc[o] = fmaf(v.y, wr[1], acc[o]);
            acc[o] = fmaf(v.z, wr[2], acc[o]);
            acc[o] = fmaf(v.w, wr[3], acc[o]);
        }
    }
    #pragma unroll
    for (int o = 0; o < COO; ++o)
        out_pre[((size_t)(n * COO + o)) * LL + l] = acc[o];
}

// ---------------- BN + relu + bilinear resize (align_corners=True) ----------------
__global__ __launch_bounds__(256) void resize_kernel(const float* __restrict__ out_pre,
                                                     const float* __restrict__ scale,
                                                     const float* __restrict__ shift,
                                                     float* __restrict__ out,
                                                     int total) {
    int idx = blockIdx.x * 256 + threadIdx.x;
    if (idx >= total) return;
    int ow = idx % HH;
    int t = idx / HH;
    int oh = t % HH;
    int t2 = t / HH;
    int o = t2 % COO;
    int n = t2 / COO;

    const float r = 63.0f / 128.0f;   // (64-1)/(129-1), exact in fp32
    float y = oh * r;
    float x = ow * r;
    int y0 = (int)y;
    int x0 = (int)x;
    float wy = y - y0;
    float wx = x - x0;
    int y1 = min(y0 + 1, 63);
    int x1 = min(x0 + 1, 63);

    const float* base = out_pre + ((size_t)(n * COO + o)) * LL;
    float sc = scale[o], sh = shift[o];
    float v00 = fmaxf(fmaf(base[y0 * 64 + x0], sc, sh), 0.0f);
    float v01 = fmaxf(fmaf(base[y0 * 64 + x1], sc, sh), 0.0f);
    float v10 = fmaxf(fmaf(base[y1 * 64 + x0], sc, sh), 0.0f);
    float v11 = fmaxf(fmaf(base[y1 * 64 + x1], sc, sh), 0.0f);
    float top = v00 * (1.0f - wx) + v01 * wx;
    float bot = v10 * (1.0f - wx) + v11 * wx;
    out[idx] = top * (1.0f - wy) + bot * wy;
}

extern "C" void kernel_launch(void* const* d_in, const int* in_sizes, int n_in,
                              void* d_out, int out_size, void* d_ws, size_t ws_size,
                              hipStream_t stream) {
    (void)in_sizes; (void)n_in; (void)out_size; (void)ws_size;
    const float* p_fea = (const float*)d_in[0];
    const float* hu    = (const float*)d_in[1];
    const float* Wq    = (const float*)d_in[2];
    const float* Wk    = (const float*)d_in[3];
    const float* Wv    = (const float*)d_in[4];
    const float* g_v   = (const float*)d_in[5];
    const float* b_v   = (const float*)d_in[6];
    const float* Wp    = (const float*)d_in[7];
    const float* g_p   = (const float*)d_in[8];
    const float* b_p   = (const float*)d_in[9];

    float* ws = (float*)d_ws;
    float* p       = ws + P_OFF;
    float* u       = ws + U_OFF;
    float* qb      = ws + Q_OFF;
    float* kb      = ws + K_OFF;
    float* val_pre = ws + VP_OFF;
    float* val_t   = ws + P_OFF;     // alias: p dead after qk/val_gemm
    float* ctx     = ws + VP_OFF;    // alias: val_pre dead after bn_apply
    float* out_pre = ws + U_OFF;     // alias: u dead after qk
    float* vscale  = ws + VSC_OFF;
    float* vshift  = ws + VSH_OFF;
    float* scale2  = ws + S2_OFF;
    float* shift2  = ws + SH2_OFF;

    pool_kernel<<<(NN * CIN * LL) / 256, 256, 0, stream>>>(p_fea, p, NN * CIN * LL);
    pool_kernel<<<(NN * CUU * LL) / 256, 256, 0, stream>>>(hu, u, NN * CUU * LL);
    qk_kernel<<<(NN * LL) / 256, 256, 0, stream>>>(p, u, Wq, Wk, qb, kb);
    val_gemm_kernel<<<512, 256, 0, stream>>>(p, Wv, val_pre);
    bn_stats_kernel<<<CVV, 256, 0, stream>>>(val_pre, g_v, b_v, vscale, vshift, CVV);
    bn_apply_kernel<<<(NN * LL * CVV) / 256, 256, 0, stream>>>(val_pre, vscale, vshift, val_t);
    attn_kernel<<<NN * (LL / 16), 256, 0, stream>>>(qb, kb, val_t, ctx);
    proj_kernel<<<(NN * LL) / 256, 256, 0, stream>>>(ctx, Wp, out_pre);
    bn_stats_kernel<<<COO, 256, 0, stream>>>(out_pre, g_p, b_p, scale2, shift2, COO);
    {
        int total = NN * COO * HH * HH;
        resize_kernel<<<(total + 255) / 256, 256, 0, stream>>>(out_pre, scale2, shift2,
                                                               (float*)d_out, total);
    }
}

// Round 2
// 308.885 us; speedup vs baseline: 3.9117x; 3.9117x over previous
//
#include <hip/hip_runtime.h>
#include <hip/hip_bf16.h>
#include <cstdint>

// Problem constants
#define NN   4
#define LL   4096      // 64*64
#define DD   18
#define CVV  128
#define CIN  256
#define CUU  10
#define HH   129
#define COO  10

typedef unsigned short ushort_t;
typedef __attribute__((ext_vector_type(8))) short short8v;   // 8 bf16 (4 VGPRs)
typedef __attribute__((ext_vector_type(4))) float f32x4;

// workspace layout (float offsets)
#define P_OFF    ((size_t)0)          // p fp32: 4*256*4096 = 4194304 (later reused as ctx: 2097152)
#define U_OFF    ((size_t)4194304)    // u fp32: 4*10*4096 = 163840 (later reused as out_pre)
#define VP_OFF   ((size_t)4358144)    // val_pre fp32: 4*128*4096 = 2097152
#define QT_OFF   ((size_t)6455296)    // qt bf16 [4][4096][32] = 524288 ushort = 262144 f
#define KT_OFF   ((size_t)6717440)    // kt bf16 [4][4096][32] = 262144 f
#define VT_OFF   ((size_t)6979584)    // vt bf16 [4][128][4096] = 2097152 ushort = 1048576 f
#define VSC_OFF  ((size_t)8028160)
#define VSH_OFF  ((size_t)8028288)
#define S2_OFF   ((size_t)8028416)
#define SH2_OFF  ((size_t)8028432)
// total ~8028448 floats = 32.1 MB

static __device__ __forceinline__ ushort_t f2bf(float x) {
    unsigned int u = __float_as_uint(x);
    unsigned int r = (u + 0x7fffu + ((u >> 16) & 1u)) >> 16;
    return (ushort_t)r;
}

// ---------------- avg pool 3x3 stride 2, VALID ----------------
__global__ __launch_bounds__(256) void pool_kernel(const float* __restrict__ src,
                                                   float* __restrict__ dst, int total) {
    int idx = blockIdx.x * 256 + threadIdx.x;
    if (idx >= total) return;
    int ow = idx & 63;
    int oh = (idx >> 6) & 63;
    int nc = idx >> 12;
    const float* s = src + (size_t)nc * (HH * HH) + (size_t)(2 * oh) * HH + 2 * ow;
    float sum = s[0] + s[1] + s[2]
              + s[HH] + s[HH + 1] + s[HH + 2]
              + s[2 * HH] + s[2 * HH + 1] + s[2 * HH + 2];
    dst[idx] = sum * (1.0f / 9.0f);
}

// ---------------- query + key 1x1 convs -> bf16, padded K-dim 18->32 ----------------
__global__ __launch_bounds__(256) void qk_kernel(const float* __restrict__ p,
                                                 const float* __restrict__ u,
                                                 const float* __restrict__ Wq,
                                                 const float* __restrict__ Wk,
                                                 ushort_t* __restrict__ qt,
                                                 ushort_t* __restrict__ kt) {
    int idx = blockIdx.x * 256 + threadIdx.x;   // over NN*LL
    int n = idx >> 12;
    int m = idx & 4095;
    int hi = m >> 6, wi = m & 63;

    float coord[8];
    coord[0] = wi * (2.0f / 64.0f) - 1.0f;
    coord[1] = hi * (2.0f / 64.0f) - 1.0f;
    coord[2] = (wi + 1) * (2.0f / 64.0f) - 1.0f;
    coord[3] = (hi + 1) * (2.0f / 64.0f) - 1.0f;
    coord[4] = 0.5f * (coord[0] + coord[2]);
    coord[5] = 0.5f * (coord[1] + coord[3]);
    coord[6] = 1.0f / 64.0f;
    coord[7] = 1.0f / 64.0f;

    // query = [u(10), coord(8)] @ Wq
    {
        float acc[DD];
        #pragma unroll
        for (int o = 0; o < DD; ++o) acc[o] = 0.0f;
        for (int c = 0; c < CUU; ++c) {
            float uv = u[((size_t)(n * CUU + c)) * LL + m];
            #pragma unroll
            for (int o = 0; o < DD; ++o) acc[o] = fmaf(uv, Wq[o * DD + c], acc[o]);
        }
        #pragma unroll
        for (int j = 0; j < 8; ++j) {
            float cv = coord[j];
            #pragma unroll
            for (int o = 0; o < DD; ++o) acc[o] = fmaf(cv, Wq[o * DD + CUU + j], acc[o]);
        }
        ushort_t* row = qt + ((size_t)(n * LL + m)) * 32;
        #pragma unroll
        for (int o = 0; o < DD; ++o) row[o] = f2bf(acc[o]);
        #pragma unroll
        for (int o = DD; o < 32; ++o) row[o] = 0;
    }
    // key = [p(256), coord(8)] @ Wk
    {
        float acc[DD];
        #pragma unroll
        for (int o = 0; o < DD; ++o) acc[o] = 0.0f;
        for (int c = 0; c < CIN; ++c) {
            float pv = p[((size_t)(n * CIN + c)) * LL + m];
            #pragma unroll
            for (int o = 0; o < DD; ++o) acc[o] = fmaf(pv, Wk[o * 264 + c], acc[o]);
        }
        #pragma unroll
        for (int j = 0; j < 8; ++j) {
            float cv = coord[j];
            #pragma unroll
            for (int o = 0; o < DD; ++o) acc[o] = fmaf(cv, Wk[o * 264 + CIN + j], acc[o]);
        }
        ushort_t* row = kt + ((size_t)(n * LL + m)) * 32;
        #pragma unroll
        for (int o = 0; o < DD; ++o) row[o] = f2bf(acc[o]);
        #pragma unroll
        for (int o = DD; o < 32; ++o) row[o] = 0;
    }
}

// ---------------- val pre-BN GEMM ----------------
__global__ __launch_bounds__(256) void val_gemm_kernel(const float* __restrict__ p,
                                                       const float* __restrict__ Wv,
                                                       float* __restrict__ val_pre) {
    int b = blockIdx.x;
    int n = b >> 7;
    int r = b & 127;
    int chb = r >> 4;
    int mb = r & 15;
    int m = mb * 256 + threadIdx.x;
    int ch0 = chb * 16;

    float acc[16];
    #pragma unroll
    for (int i = 0; i < 16; ++i) acc[i] = 0.0f;

    for (int c = 0; c < CIN; ++c) {
        float pv = p[((size_t)(n * CIN + c)) * LL + m];
        #pragma unroll
        for (int i = 0; i < 16; ++i)
            acc[i] = fmaf(pv, Wv[(ch0 + i) * CIN + c], acc[i]);
    }
    #pragma unroll
    for (int i = 0; i < 16; ++i)
        val_pre[((size_t)(n * CVV + ch0 + i)) * LL + m] = acc[i];
}

// ---------------- BN stats over (N, L) per channel ----------------
__global__ __launch_bounds__(256) void bn_stats_kernel(const float* __restrict__ src,
                                                       const float* __restrict__ g,
                                                       const float* __restrict__ bta,
                                                       float* __restrict__ scale,
                                                       float* __restrict__ shift,
                                                       int C) {
    int ch = blockIdx.x;
    float s = 0.0f, s2 = 0.0f;
    for (int i = threadIdx.x; i < NN * LL; i += 256) {
        int n = i >> 12;
        int m = i & 4095;
        float v = src[((size_t)(n * C + ch)) * LL + m];
        s += v;
        s2 = fmaf(v, v, s2);
    }
    __shared__ float rs[4], rs2[4];
    #pragma unroll
    for (int off = 32; off; off >>= 1) {
        s += __shfl_down(s, off);
        s2 += __shfl_down(s2, off);
    }
    int wid = threadIdx.x >> 6;
    if ((threadIdx.x & 63) == 0) { rs[wid] = s; rs2[wid] = s2; }
    __syncthreads();
    if (threadIdx.x == 0) {
        s = rs[0] + rs[1] + rs[2] + rs[3];
        s2 = rs2[0] + rs2[1] + rs2[2] + rs2[3];
        float mean = s * (1.0f / (NN * LL));
        float var = s2 * (1.0f / (NN * LL)) - mean * mean;
        float inv = rsqrtf(var + 1e-5f);
        float sc = g[ch] * inv;
        scale[ch] = sc;
        shift[ch] = bta[ch] - mean * sc;
    }
}

// ---------------- apply BN + relu -> bf16 V, layout [n][c][m] ----------------
__global__ __launch_bounds__(256) void bn_apply_kernel(const float* __restrict__ val_pre,
                                                       const float* __restrict__ scale,
                                                       const float* __restrict__ shift,
                                                       ushort_t* __restrict__ vt) {
    int t = blockIdx.x * 256 + threadIdx.x;   // over NN*CVV*LL, m fastest
    int m = t & 4095;
    int ch = (t >> 12) & 127;
    int n = t >> 19;
    size_t i = ((size_t)(n * CVV + ch)) * LL + m;
    float v = val_pre[i];
    v = fmaf(v, scale[ch], shift[ch]);
    vt[i] = f2bf(fmaxf(v, 0.0f));
}

// ---------------- flash attention via MFMA ----------------
// grid: 4n * 128 = 512 blocks, 256 threads = 4 waves.
// wave w: q-tile = (blk&127)*32 + (w>>1)*16 rows; m-split s = w&1 covers m in [s*2048, s*2048+2048)
__global__ __launch_bounds__(256) void attn_mfma_kernel(const ushort_t* __restrict__ qt,
                                                        const ushort_t* __restrict__ kt,
                                                        const ushort_t* __restrict__ vt,
                                                        float* __restrict__ ctx) {
    int b = blockIdx.x;
    int n = b >> 7;
    int qt2 = b & 127;
    int tid = threadIdx.x;
    int w = tid >> 6;
    int qtl = w >> 1;
    int s = w & 1;
    int lane = tid & 63;
    int c = lane & 15;
    int g = lane >> 4;

    int l0 = qt2 * 32 + qtl * 16;
    int m_base = s * 2048;

    __shared__ ushort_t p_lds[4][16][72];     // per-wave P tile, padded
    __shared__ float scrO[2][16][132];
    __shared__ float scrM[2][16], scrL[2][16];

    // Q A-fragment: row = lane%16, k = 8*(lane>>4)+i
    short8v qf = *(const short8v*)(qt + (((size_t)(n * LL) + l0 + c) << 5) + g * 8);

    f32x4 O[8];
    #pragma unroll
    for (int i = 0; i < 8; ++i) O[i] = (f32x4){0.f, 0.f, 0.f, 0.f};
    float M[4] = {-3.0e38f, -3.0e38f, -3.0e38f, -3.0e38f};
    float Lp[4] = {0.f, 0.f, 0.f, 0.f};

    const ushort_t* ktn = kt + ((size_t)(n * LL) << 5);
    const ushort_t* vtn = vt + ((size_t)n * CVV) * LL;

    for (int mt = 0; mt < 32; ++mt) {
        int m0 = m_base + mt * 64;
        // ---- energy: S[t] = Q(16x32) * K^T(32x16) ----
        f32x4 S[4];
        #pragma unroll
        for (int t = 0; t < 4; ++t) {
            short8v kf = *(const short8v*)(ktn + (((size_t)(m0 + t * 16 + c)) << 5) + g * 8);
            S[t] = __builtin_amdgcn_mfma_f32_16x16x32_bf16(qf, kf, (f32x4){0.f, 0.f, 0.f, 0.f}, 0, 0, 0);
        }
        // ---- online softmax (rows live on (g,reg), cols on lanes&15 x 4 subtiles) ----
        float tm[4];
        #pragma unroll
        for (int r = 0; r < 4; ++r)
            tm[r] = fmaxf(fmaxf(S[0][r], S[1][r]), fmaxf(S[2][r], S[3][r]));
        #pragma unroll
        for (int off = 1; off < 16; off <<= 1) {
            #pragma unroll
            for (int r = 0; r < 4; ++r) tm[r] = fmaxf(tm[r], __shfl_xor(tm[r], off));
        }
        float Mn[4], f[4];
        #pragma unroll
        for (int r = 0; r < 4; ++r) {
            Mn[r] = fmaxf(M[r], tm[r]);
            f[r] = __expf(M[r] - Mn[r]);   // ==1 when no new max
            M[r] = Mn[r];
            Lp[r] *= f[r];
        }
        #pragma unroll
        for (int ct = 0; ct < 8; ++ct) {
            #pragma unroll
            for (int r = 0; r < 4; ++r) O[ct][r] *= f[r];
        }
        #pragma unroll
        for (int t = 0; t < 4; ++t) {
            #pragma unroll
            for (int r = 0; r < 4; ++r) {
                float pv = __expf(S[t][r] - Mn[r]);
                Lp[r] += pv;
                p_lds[w][g * 4 + r][t * 16 + c] = f2bf(pv);
            }
        }
        // ---- P back as A-fragments ----
        short8v pa0 = *(const short8v*)&p_lds[w][c][g * 8];
        short8v pa1 = *(const short8v*)&p_lds[w][c][32 + g * 8];
        // ---- PV: O[ct] += P(16x64) * V(64x16) ----
        const ushort_t* vb = vtn + m0 + g * 8;
        #pragma unroll
        for (int ct = 0; ct < 8; ++ct) {
            short8v v0 = *(const short8v*)(vb + ((size_t)(ct * 16 + c)) * LL);
            short8v v1 = *(const short8v*)(vb + ((size_t)(ct * 16 + c)) * LL + 32);
            O[ct] = __builtin_amdgcn_mfma_f32_16x16x32_bf16(pa0, v0, O[ct], 0, 0, 0);
            O[ct] = __builtin_amdgcn_mfma_f32_16x16x32_bf16(pa1, v1, O[ct], 0, 0, 0);
        }
    }

    // ---- row-sum across the 16 lanes of each group ----
    #pragma unroll
    for (int off = 1; off < 16; off <<= 1) {
        #pragma unroll
        for (int r = 0; r < 4; ++r) Lp[r] += __shfl_xor(Lp[r], off);
    }

    // ---- combine the two m-splits ----
    if (s == 1) {
        if (c == 0) {
            #pragma unroll
            for (int r = 0; r < 4; ++r) { scrM[qtl][g * 4 + r] = M[r]; scrL[qtl][g * 4 + r] = Lp[r]; }
        }
        #pragma unroll
        for (int ct = 0; ct < 8; ++ct)
            #pragma unroll
            for (int r = 0; r < 4; ++r)
                scrO[qtl][g * 4 + r][ct * 16 + c] = O[ct][r];
    }
    __syncthreads();
    if (s == 0) {
        float a1[4], a2[4];
        #pragma unroll
        for (int r = 0; r < 4; ++r) {
            float M2 = scrM[qtl][g * 4 + r];
            float L2 = scrL[qtl][g * 4 + r];
            float Mf = fmaxf(M[r], M2);
            float e1 = __expf(M[r] - Mf);
            float e2 = __expf(M2 - Mf);
            float inv = 1.0f / (Lp[r] * e1 + L2 * e2);
            a1[r] = e1 * inv;
            a2[r] = e2 * inv;
        }
        #pragma unroll
        for (int ct = 0; ct < 8; ++ct)
            #pragma unroll
            for (int r = 0; r < 4; ++r)
                ctx[((size_t)(n * LL) + l0 + g * 4 + r) * CVV + ct * 16 + c] =
                    O[ct][r] * a1[r] + scrO[qtl][g * 4 + r][ct * 16 + c] * a2[r];
    }
}

// ---------------- projection ----------------
__global__ __launch_bounds__(256) void proj_kernel(const float* __restrict__ ctx,
                                                   const float* __restrict__ Wp,
                                                   float* __restrict__ out_pre) {
    int idx = blockIdx.x * 256 + threadIdx.x;   // over NN*LL
    int n = idx >> 12;
    int l = idx & 4095;
    const float4* r4 = (const float4*)(ctx + ((size_t)(n * LL + l)) * CVV);
    float acc[COO];
    #pragma unroll
    for (int o = 0; o < COO; ++o) acc[o] = 0.0f;
    for (int c4 = 0; c4 < CVV / 4; ++c4) {
        float4 v = r4[c4];
        #pragma unroll
        for (int o = 0; o < COO; ++o) {
            const float* wr = Wp + o * CVV + c4 * 4;
            acc[o] = fmaf(v.x, wr[0], acc[o]);
            acc[o] = fmaf(v.y, wr[1], acc[o]);
            acc[o] = fmaf(v.z, wr[2], acc[o]);
            acc[o] = fmaf(v.w, wr[3], acc[o]);
        }
    }
    #pragma unroll
    for (int o = 0; o < COO; ++o)
        out_pre[((size_t)(n * COO + o)) * LL + l] = acc[o];
}

// ---------------- BN + relu + bilinear resize (align_corners=True) ----------------
__global__ __launch_bounds__(256) void resize_kernel(const float* __restrict__ out_pre,
                                                     const float* __restrict__ scale,
                                                     const float* __restrict__ shift,
                                                     float* __restrict__ out,
                                                     int total) {
    int idx = blockIdx.x * 256 + threadIdx.x;
    if (idx >= total) return;
    int ow = idx % HH;
    int t = idx / HH;
    int oh = t % HH;
    int t2 = t / HH;
    int o = t2 % COO;
    int n = t2 / COO;

    const float r = 63.0f / 128.0f;
    float y = oh * r;
    float x = ow * r;
    int y0 = (int)y;
    int x0 = (int)x;
    float wy = y - y0;
    float wx = x - x0;
    int y1 = min(y0 + 1, 63);
    int x1 = min(x0 + 1, 63);

    const float* base = out_pre + ((size_t)(n * COO + o)) * LL;
    float sc = scale[o], sh = shift[o];
    float v00 = fmaxf(fmaf(base[y0 * 64 + x0], sc, sh), 0.0f);
    float v01 = fmaxf(fmaf(base[y0 * 64 + x1], sc, sh), 0.0f);
    float v10 = fmaxf(fmaf(base[y1 * 64 + x0], sc, sh), 0.0f);
    float v11 = fmaxf(fmaf(base[y1 * 64 + x1], sc, sh), 0.0f);
    float top = v00 * (1.0f - wx) + v01 * wx;
    float bot = v10 * (1.0f - wx) + v11 * wx;
    out[idx] = top * (1.0f - wy) + bot * wy;
}

extern "C" void kernel_launch(void* const* d_in, const int* in_sizes, int n_in,
                              void* d_out, int out_size, void* d_ws, size_t ws_size,
                              hipStream_t stream) {
    (void)in_sizes; (void)n_in; (void)out_size; (void)ws_size;
    const float* p_fea = (const float*)d_in[0];
    const float* hu    = (const float*)d_in[1];
    const float* Wq    = (const float*)d_in[2];
    const float* Wk    = (const float*)d_in[3];
    const float* Wv    = (const float*)d_in[4];
    const float* g_v   = (const float*)d_in[5];
    const float* b_v   = (const float*)d_in[6];
    const float* Wp    = (const float*)d_in[7];
    const float* g_p   = (const float*)d_in[8];
    const float* b_p   = (const float*)d_in[9];

    float* ws = (float*)d_ws;
    float*    p       = ws + P_OFF;
    float*    u       = ws + U_OFF;
    float*    val_pre = ws + VP_OFF;
    ushort_t* qtb     = (ushort_t*)(ws + QT_OFF);
    ushort_t* ktb     = (ushort_t*)(ws + KT_OFF);
    ushort_t* vtb     = (ushort_t*)(ws + VT_OFF);
    float*    ctx     = ws + P_OFF;     // alias: p dead after qk/val_gemm
    float*    out_pre = ws + U_OFF;     // alias: u dead after qk
    float*    vscale  = ws + VSC_OFF;
    float*    vshift  = ws + VSH_OFF;
    float*    scale2  = ws + S2_OFF;
    float*    shift2  = ws + SH2_OFF;

    pool_kernel<<<(NN * CIN * LL) / 256, 256, 0, stream>>>(p_fea, p, NN * CIN * LL);
    pool_kernel<<<(NN * CUU * LL) / 256, 256, 0, stream>>>(hu, u, NN * CUU * LL);
    qk_kernel<<<(NN * LL) / 256, 256, 0, stream>>>(p, u, Wq, Wk, qtb, ktb);
    val_gemm_kernel<<<512, 256, 0, stream>>>(p, Wv, val_pre);
    bn_stats_kernel<<<CVV, 256, 0, stream>>>(val_pre, g_v, b_v, vscale, vshift, CVV);
    bn_apply_kernel<<<(NN * CVV * LL) / 256, 256, 0, stream>>>(val_pre, vscale, vshift, vtb);
    attn_mfma_kernel<<<512, 256, 0, stream>>>(qtb, ktb, vtb, ctx);
    proj_kernel<<<(NN * LL) / 256, 256, 0, stream>>>(ctx, Wp, out_pre);
    bn_stats_kernel<<<COO, 256, 0, stream>>>(out_pre, g_p, b_p, scale2, shift2, COO);
    {
        int total = NN * COO * HH * HH;
        resize_kernel<<<(total + 255) / 256, 256, 0, stream>>>(out_pre, scale2, shift2,
                                                               (float*)d_out, total);
    }
}

// Round 3
// 280.984 us; speedup vs baseline: 4.3001x; 1.0993x over previous
//
#include <hip/hip_runtime.h>
#include <hip/hip_bf16.h>
#include <cstdint>

// Problem constants
#define NN   4
#define LL   4096      // 64*64
#define DD   18
#define CVV  128
#define CIN  256
#define CUU  10
#define HH   129
#define COO  10

typedef unsigned short ushort_t;
typedef __attribute__((ext_vector_type(8))) short short8v;   // 8 bf16 (4 VGPRs)
typedef __attribute__((ext_vector_type(4))) float f32x4;

// workspace layout (float offsets)
#define P_OFF    ((size_t)0)          // p fp32: 4*256*4096 = 4194304 (later reused as ctx)
#define U_OFF    ((size_t)4194304)    // u fp32: 163840 (later reused as out_pre)
#define VP_OFF   ((size_t)4358144)    // val_pre fp32: 2097152
#define QT_OFF   ((size_t)6455296)    // qt bf16 [4][4096][32] = 262144 f
#define KT_OFF   ((size_t)6717440)    // kt bf16 [4][4096][32] = 262144 f
#define VT_OFF   ((size_t)6979584)    // vt bf16 [4][128][4096] = 1048576 f
#define VSC_OFF  ((size_t)8028160)
#define VSH_OFF  ((size_t)8028288)
#define S2_OFF   ((size_t)8028416)
#define SH2_OFF  ((size_t)8028432)
#define PART_OFF ((size_t)8028448)    // bn partials: C*8*2 <= 2048 floats
// total ~8030496 floats = 32.1 MB

static __device__ __forceinline__ ushort_t f2bf(float x) {
    unsigned int u = __float_as_uint(x);
    unsigned int r = (u + 0x7fffu + ((u >> 16) & 1u)) >> 16;
    return (ushort_t)r;
}

// ---------------- avg pool 3x3 stride 2 with LDS row staging ----------------
// block: one (n,c) plane x 4 output rows. grid = NN*C*16.
__global__ __launch_bounds__(256) void pool2_kernel(const float* __restrict__ src,
                                                    float* __restrict__ dst) {
    int b = blockIdx.x;
    int plane = b >> 4;
    int rg = b & 15;
    __shared__ float rows[9][132];
    const float* sp = src + (size_t)plane * (HH * HH) + (size_t)(rg * 8) * HH;
    #pragma unroll
    for (int j = 0; j < 9; ++j) {
        if (threadIdx.x < HH) rows[j][threadIdx.x] = sp[(size_t)j * HH + threadIdx.x];
    }
    __syncthreads();
    int row = threadIdx.x >> 6, ow = threadIdx.x & 63;
    const float* r0 = rows[2 * row];
    const float* r1 = rows[2 * row + 1];
    const float* r2 = rows[2 * row + 2];
    int x = 2 * ow;
    float sum = r0[x] + r0[x + 1] + r0[x + 2]
              + r1[x] + r1[x + 1] + r1[x + 2]
              + r2[x] + r2[x + 1] + r2[x + 2];
    dst[(size_t)plane * 4096 + (size_t)(rg * 4 + row) * 64 + ow] = sum * (1.0f / 9.0f);
}

// ---------------- query + key 1x1 convs -> bf16, padded K-dim 18->32 ----------------
__global__ __launch_bounds__(256) void qk_kernel(const float* __restrict__ p,
                                                 const float* __restrict__ u,
                                                 const float* __restrict__ Wq,
                                                 const float* __restrict__ Wk,
                                                 ushort_t* __restrict__ qt,
                                                 ushort_t* __restrict__ kt) {
    int idx = blockIdx.x * 256 + threadIdx.x;   // over NN*LL
    int n = idx >> 12;
    int m = idx & 4095;
    int hi = m >> 6, wi = m & 63;

    float coord[8];
    coord[0] = wi * (2.0f / 64.0f) - 1.0f;
    coord[1] = hi * (2.0f / 64.0f) - 1.0f;
    coord[2] = (wi + 1) * (2.0f / 64.0f) - 1.0f;
    coord[3] = (hi + 1) * (2.0f / 64.0f) - 1.0f;
    coord[4] = 0.5f * (coord[0] + coord[2]);
    coord[5] = 0.5f * (coord[1] + coord[3]);
    coord[6] = 1.0f / 64.0f;
    coord[7] = 1.0f / 64.0f;

    {
        float acc[DD];
        #pragma unroll
        for (int o = 0; o < DD; ++o) acc[o] = 0.0f;
        for (int c = 0; c < CUU; ++c) {
            float uv = u[((size_t)(n * CUU + c)) * LL + m];
            #pragma unroll
            for (int o = 0; o < DD; ++o) acc[o] = fmaf(uv, Wq[o * DD + c], acc[o]);
        }
        #pragma unroll
        for (int j = 0; j < 8; ++j) {
            float cv = coord[j];
            #pragma unroll
            for (int o = 0; o < DD; ++o) acc[o] = fmaf(cv, Wq[o * DD + CUU + j], acc[o]);
        }
        ushort_t* row = qt + ((size_t)(n * LL + m)) * 32;
        #pragma unroll
        for (int o = 0; o < DD; ++o) row[o] = f2bf(acc[o]);
        #pragma unroll
        for (int o = DD; o < 32; ++o) row[o] = 0;
    }
    {
        float acc[DD];
        #pragma unroll
        for (int o = 0; o < DD; ++o) acc[o] = 0.0f;
        for (int c = 0; c < CIN; ++c) {
            float pv = p[((size_t)(n * CIN + c)) * LL + m];
            #pragma unroll
            for (int o = 0; o < DD; ++o) acc[o] = fmaf(pv, Wk[o * 264 + c], acc[o]);
        }
        #pragma unroll
        for (int j = 0; j < 8; ++j) {
            float cv = coord[j];
            #pragma unroll
            for (int o = 0; o < DD; ++o) acc[o] = fmaf(cv, Wk[o * 264 + CIN + j], acc[o]);
        }
        ushort_t* row = kt + ((size_t)(n * LL + m)) * 32;
        #pragma unroll
        for (int o = 0; o < DD; ++o) row[o] = f2bf(acc[o]);
        #pragma unroll
        for (int o = DD; o < 32; ++o) row[o] = 0;
    }
}

// ---------------- val pre-BN GEMM ----------------
__global__ __launch_bounds__(256) void val_gemm_kernel(const float* __restrict__ p,
                                                       const float* __restrict__ Wv,
                                                       float* __restrict__ val_pre) {
    int b = blockIdx.x;
    int n = b >> 7;
    int r = b & 127;
    int chb = r >> 4;
    int mb = r & 15;
    int m = mb * 256 + threadIdx.x;
    int ch0 = chb * 16;

    float acc[16];
    #pragma unroll
    for (int i = 0; i < 16; ++i) acc[i] = 0.0f;

    for (int c = 0; c < CIN; ++c) {
        float pv = p[((size_t)(n * CIN + c)) * LL + m];
        #pragma unroll
        for (int i = 0; i < 16; ++i)
            acc[i] = fmaf(pv, Wv[(ch0 + i) * CIN + c], acc[i]);
    }
    #pragma unroll
    for (int i = 0; i < 16; ++i)
        val_pre[((size_t)(n * CVV + ch0 + i)) * LL + m] = acc[i];
}

// ---------------- BN stats, two-stage ----------------
__global__ __launch_bounds__(256) void bn_partial_kernel(const float* __restrict__ src,
                                                         float* __restrict__ part, int C) {
    int ch = blockIdx.x >> 3;
    int s = blockIdx.x & 7;
    float s1 = 0.0f, s2 = 0.0f;
    #pragma unroll
    for (int k = 0; k < 8; ++k) {
        int e = s * 2048 + k * 256 + threadIdx.x;
        int n = e >> 12;
        int m = e & 4095;
        float v = src[((size_t)(n * C + ch)) * LL + m];
        s1 += v;
        s2 = fmaf(v, v, s2);
    }
    __shared__ float rs[4], rs2[4];
    #pragma unroll
    for (int off = 32; off; off >>= 1) {
        s1 += __shfl_down(s1, off);
        s2 += __shfl_down(s2, off);
    }
    int wid = threadIdx.x >> 6;
    if ((threadIdx.x & 63) == 0) { rs[wid] = s1; rs2[wid] = s2; }
    __syncthreads();
    if (threadIdx.x == 0) {
        part[(size_t)blockIdx.x * 2]     = rs[0] + rs[1] + rs[2] + rs[3];
        part[(size_t)blockIdx.x * 2 + 1] = rs2[0] + rs2[1] + rs2[2] + rs2[3];
    }
}

__global__ __launch_bounds__(128) void bn_finalize_kernel(const float* __restrict__ part,
                                                          const float* __restrict__ g,
                                                          const float* __restrict__ bta,
                                                          float* __restrict__ scale,
                                                          float* __restrict__ shift, int C) {
    int ch = threadIdx.x;
    if (ch >= C) return;
    float s1 = 0.0f, s2 = 0.0f;
    #pragma unroll
    for (int s = 0; s < 8; ++s) {
        s1 += part[(size_t)(ch * 8 + s) * 2];
        s2 += part[(size_t)(ch * 8 + s) * 2 + 1];
    }
    float mean = s1 * (1.0f / (NN * LL));
    float var = s2 * (1.0f / (NN * LL)) - mean * mean;
    float inv = rsqrtf(var + 1e-5f);
    float sc = g[ch] * inv;
    scale[ch] = sc;
    shift[ch] = bta[ch] - mean * sc;
}

// ---------------- apply BN + relu -> bf16 V, layout [n][c][m] ----------------
__global__ __launch_bounds__(256) void bn_apply_kernel(const float* __restrict__ val_pre,
                                                       const float* __restrict__ scale,
                                                       const float* __restrict__ shift,
                                                       ushort_t* __restrict__ vt) {
    int t = blockIdx.x * 256 + threadIdx.x;   // over NN*CVV*LL, m fastest
    int m = t & 4095;
    int ch = (t >> 12) & 127;
    int n = t >> 19;
    size_t i = ((size_t)(n * CVV + ch)) * LL + m;
    float v = val_pre[i];
    v = fmaf(v, scale[ch], shift[ch]);
    vt[i] = f2bf(fmaxf(v, 0.0f));
}

// ---------------- flash attention via MFMA, two-pass fixed-max, 4-way m-split ----------------
// grid: 4n * 256 qtiles = 1024 blocks, 256 threads = 4 waves.
// wave w covers m in [w*1024, (w+1)*1024); all waves share the block's 16 q-rows.
struct AttnWS {
    union {
        ushort_t p[16][72];                                 // P tile (pass 2)
        struct { float O[16][132]; float M[16]; float L[16]; } cmb;   // combine
    };
};

__global__ __launch_bounds__(256, 4) void attn_mfma2_kernel(const ushort_t* __restrict__ qt,
                                                            const ushort_t* __restrict__ kt,
                                                            const ushort_t* __restrict__ vt,
                                                            float* __restrict__ ctx) {
    int b = blockIdx.x;
    int n = b >> 8;
    int qti = b & 255;
    int l0 = qti * 16;
    int tid = threadIdx.x;
    int w = tid >> 6;
    int lane = tid & 63;
    int c = lane & 15;
    int g = lane >> 4;

    __shared__ AttnWS u[4];

    int m_base = w * 1024;
    const ushort_t* ktn = kt + ((size_t)(n * LL) << 5);
    const ushort_t* vtn = vt + ((size_t)n * CVV) * LL;

    // Q A-fragment: row = lane&15, k = 8*(lane>>4)+i
    short8v qf = *(const short8v*)(qt + (((size_t)(n * LL) + l0 + c) << 5) + g * 8);

    // ---- pass 1: per-lane row max (no cross-lane ops in loop) ----
    float M[4] = {-3.0e38f, -3.0e38f, -3.0e38f, -3.0e38f};
    for (int mt = 0; mt < 16; ++mt) {
        int m0 = m_base + mt * 64;
        #pragma unroll
        for (int t = 0; t < 4; ++t) {
            short8v kf = *(const short8v*)(ktn + (((size_t)(m0 + t * 16 + c)) << 5) + g * 8);
            f32x4 S = __builtin_amdgcn_mfma_f32_16x16x32_bf16(qf, kf, (f32x4){0.f, 0.f, 0.f, 0.f}, 0, 0, 0);
            #pragma unroll
            for (int r = 0; r < 4; ++r) M[r] = fmaxf(M[r], S[r]);
        }
    }
    // merge max across the 16 column-lanes (rows live on (g,r))
    #pragma unroll
    for (int off = 1; off < 16; off <<= 1) {
        #pragma unroll
        for (int r = 0; r < 4; ++r) M[r] = fmaxf(M[r], __shfl_xor(M[r], off));
    }

    // ---- pass 2: P = exp(S-M) (unnormalized), accumulate O and L ----
    f32x4 O[8];
    #pragma unroll
    for (int i = 0; i < 8; ++i) O[i] = (f32x4){0.f, 0.f, 0.f, 0.f};
    float Lp[4] = {0.f, 0.f, 0.f, 0.f};

    for (int mt = 0; mt < 16; ++mt) {
        int m0 = m_base + mt * 64;
        f32x4 S[4];
        #pragma unroll
        for (int t = 0; t < 4; ++t) {
            short8v kf = *(const short8v*)(ktn + (((size_t)(m0 + t * 16 + c)) << 5) + g * 8);
            S[t] = __builtin_amdgcn_mfma_f32_16x16x32_bf16(qf, kf, (f32x4){0.f, 0.f, 0.f, 0.f}, 0, 0, 0);
        }
        #pragma unroll
        for (int t = 0; t < 4; ++t) {
            #pragma unroll
            for (int r = 0; r < 4; ++r) {
                float pv = __expf(S[t][r] - M[r]);
                Lp[r] += pv;
                u[w].p[g * 4 + r][t * 16 + c] = f2bf(pv);
            }
        }
        short8v pa0 = *(const short8v*)&u[w].p[c][g * 8];
        short8v pa1 = *(const short8v*)&u[w].p[c][32 + g * 8];
        const ushort_t* vb = vtn + m0 + g * 8;
        #pragma unroll
        for (int ct = 0; ct < 8; ++ct) {
            short8v v0 = *(const short8v*)(vb + ((size_t)(ct * 16 + c)) * LL);
            short8v v1 = *(const short8v*)(vb + ((size_t)(ct * 16 + c)) * LL + 32);
            O[ct] = __builtin_amdgcn_mfma_f32_16x16x32_bf16(pa0, v0, O[ct], 0, 0, 0);
            O[ct] = __builtin_amdgcn_mfma_f32_16x16x32_bf16(pa1, v1, O[ct], 0, 0, 0);
        }
    }
    // row-sum of L across column-lanes
    #pragma unroll
    for (int off = 1; off < 16; off <<= 1) {
        #pragma unroll
        for (int r = 0; r < 4; ++r) Lp[r] += __shfl_xor(Lp[r], off);
    }

    // ---- write per-wave state; combine across the 4 m-splits ----
    #pragma unroll
    for (int ct = 0; ct < 8; ++ct)
        #pragma unroll
        for (int r = 0; r < 4; ++r)
            u[w].cmb.O[g * 4 + r][ct * 16 + c] = O[ct][r];
    if (c == 0) {
        #pragma unroll
        for (int r = 0; r < 4; ++r) { u[w].cmb.M[g * 4 + r] = M[r]; u[w].cmb.L[g * 4 + r] = Lp[r]; }
    }
    __syncthreads();

    int l = tid >> 4;
    int c0 = (tid & 15) * 8;
    float Mstar = fmaxf(fmaxf(u[0].cmb.M[l], u[1].cmb.M[l]), fmaxf(u[2].cmb.M[l], u[3].cmb.M[l]));
    float wgt[4], Lt = 0.0f;
    #pragma unroll
    for (int s = 0; s < 4; ++s) {
        wgt[s] = __expf(u[s].cmb.M[l] - Mstar);
        Lt = fmaf(wgt[s], u[s].cmb.L[l], Lt);
    }
    float inv = 1.0f / Lt;
    float o[8];
    #pragma unroll
    for (int j = 0; j < 8; ++j) o[j] = 0.0f;
    #pragma unroll
    for (int s = 0; s < 4; ++s) {
        const float* Or = &u[s].cmb.O[l][c0];
        #pragma unroll
        for (int j = 0; j < 8; ++j) o[j] = fmaf(wgt[s], Or[j], o[j]);
    }
    size_t rowo = ((size_t)(n * LL) + l0 + l) * CVV + c0;
    *(float4*)&ctx[rowo]     = make_float4(o[0] * inv, o[1] * inv, o[2] * inv, o[3] * inv);
    *(float4*)&ctx[rowo + 4] = make_float4(o[4] * inv, o[5] * inv, o[6] * inv, o[7] * inv);
}

// ---------------- projection ----------------
__global__ __launch_bounds__(256) void proj_kernel(const float* __restrict__ ctx,
                                                   const float* __restrict__ Wp,
                                                   float* __restrict__ out_pre) {
    int idx = blockIdx.x * 256 + threadIdx.x;   // over NN*LL
    int n = idx >> 12;
    int l = idx & 4095;
    const float4* r4 = (const float4*)(ctx + ((size_t)(n * LL + l)) * CVV);
    float acc[COO];
    #pragma unroll
    for (int o = 0; o < COO; ++o) acc[o] = 0.0f;
    for (int c4 = 0; c4 < CVV / 4; ++c4) {
        float4 v = r4[c4];
        #pragma unroll
        for (int o = 0; o < COO; ++o) {
            const float* wr = Wp + o * CVV + c4 * 4;
            acc[o] = fmaf(v.x, wr[0], acc[o]);
            acc[o] = fmaf(v.y, wr[1], acc[o]);
            acc[o] = fmaf(v.z, wr[2], acc[o]);
            acc[o] = fmaf(v.w, wr[3], acc[o]);
        }
    }
    #pragma unroll
    for (int o = 0; o < COO; ++o)
        out_pre[((size_t)(n * COO + o)) * LL + l] = acc[o];
}

// ---------------- BN + relu + bilinear resize (align_corners=True) ----------------
__global__ __launch_bounds__(256) void resize_kernel(const float* __restrict__ out_pre,
                                                     const float* __restrict__ scale,
                                                     const float* __restrict__ shift,
                                                     float* __restrict__ out,
                                                     int total) {
    int idx = blockIdx.x * 256 + threadIdx.x;
    if (idx >= total) return;
    int ow = idx % HH;
    int t = idx / HH;
    int oh = t % HH;
    int t2 = t / HH;
    int o = t2 % COO;
    int n = t2 / COO;

    const float r = 63.0f / 128.0f;
    float y = oh * r;
    float x = ow * r;
    int y0 = (int)y;
    int x0 = (int)x;
    float wy = y - y0;
    float wx = x - x0;
    int y1 = min(y0 + 1, 63);
    int x1 = min(x0 + 1, 63);

    const float* base = out_pre + ((size_t)(n * COO + o)) * LL;
    float sc = scale[o], sh = shift[o];
    float v00 = fmaxf(fmaf(base[y0 * 64 + x0], sc, sh), 0.0f);
    float v01 = fmaxf(fmaf(base[y0 * 64 + x1], sc, sh), 0.0f);
    float v10 = fmaxf(fmaf(base[y1 * 64 + x0], sc, sh), 0.0f);
    float v11 = fmaxf(fmaf(base[y1 * 64 + x1], sc, sh), 0.0f);
    float top = v00 * (1.0f - wx) + v01 * wx;
    float bot = v10 * (1.0f - wx) + v11 * wx;
    out[idx] = top * (1.0f - wy) + bot * wy;
}

extern "C" void kernel_launch(void* const* d_in, const int* in_sizes, int n_in,
                              void* d_out, int out_size, void* d_ws, size_t ws_size,
                              hipStream_t stream) {
    (void)in_sizes; (void)n_in; (void)out_size; (void)ws_size;
    const float* p_fea = (const float*)d_in[0];
    const float* hu    = (const float*)d_in[1];
    const float* Wq    = (const float*)d_in[2];
    const float* Wk    = (const float*)d_in[3];
    const float* Wv    = (const float*)d_in[4];
    const float* g_v   = (const float*)d_in[5];
    const float* b_v   = (const float*)d_in[6];
    const float* Wp    = (const float*)d_in[7];
    const float* g_p   = (const float*)d_in[8];
    const float* b_p   = (const float*)d_in[9];

    float* ws = (float*)d_ws;
    float*    p       = ws + P_OFF;
    float*    u       = ws + U_OFF;
    float*    val_pre = ws + VP_OFF;
    ushort_t* qtb     = (ushort_t*)(ws + QT_OFF);
    ushort_t* ktb     = (ushort_t*)(ws + KT_OFF);
    ushort_t* vtb     = (ushort_t*)(ws + VT_OFF);
    float*    ctx     = ws + P_OFF;     // alias: p dead after qk/val_gemm
    float*    out_pre = ws + U_OFF;     // alias: u dead after qk
    float*    vscale  = ws + VSC_OFF;
    float*    vshift  = ws + VSH_OFF;
    float*    scale2  = ws + S2_OFF;
    float*    shift2  = ws + SH2_OFF;
    float*    part    = ws + PART_OFF;

    pool2_kernel<<<NN * CIN * 16, 256, 0, stream>>>(p_fea, p);
    pool2_kernel<<<NN * CUU * 16, 256, 0, stream>>>(hu, u);
    qk_kernel<<<(NN * LL) / 256, 256, 0, stream>>>(p, u, Wq, Wk, qtb, ktb);
    val_gemm_kernel<<<512, 256, 0, stream>>>(p, Wv, val_pre);
    bn_partial_kernel<<<CVV * 8, 256, 0, stream>>>(val_pre, part, CVV);
    bn_finalize_kernel<<<1, 128, 0, stream>>>(part, g_v, b_v, vscale, vshift, CVV);
    bn_apply_kernel<<<(NN * CVV * LL) / 256, 256, 0, stream>>>(val_pre, vscale, vshift, vtb);
    attn_mfma2_kernel<<<1024, 256, 0, stream>>>(qtb, ktb, vtb, ctx);
    proj_kernel<<<(NN * LL) / 256, 256, 0, stream>>>(ctx, Wp, out_pre);
    bn_partial_kernel<<<COO * 8, 256, 0, stream>>>(out_pre, part, COO);
    bn_finalize_kernel<<<1, 128, 0, stream>>>(part, g_p, b_p, scale2, shift2, COO);
    {
        int total = NN * COO * HH * HH;
        resize_kernel<<<(total + 255) / 256, 256, 0, stream>>>(out_pre, scale2, shift2,
                                                               (float*)d_out, total);
    }
}

// Round 4
// 202.165 us; speedup vs baseline: 5.9766x; 1.3899x over previous
//
#include <hip/hip_runtime.h>
#include <hip/hip_bf16.h>
#include <cstdint>

// Problem constants
#define NN   4
#define LL   4096      // 64*64
#define DD   18
#define CVV  128
#define CIN  256
#define CUU  10
#define HH   129
#define COO  10

typedef unsigned short ushort_t;
typedef __attribute__((ext_vector_type(8))) short short8v;   // 8 bf16 (4 VGPRs)
typedef __attribute__((ext_vector_type(4))) float f32x4;

// workspace layout (float offsets)
#define P_OFF    ((size_t)0)          // p fp32 4*256*4096 = 4194304 f (later: Opart [2][4][4096][128] = 4194304 f)
#define U_OFF    ((size_t)4194304)    // u fp32 163840 f (later out_pre)
#define VP_OFF   ((size_t)4358144)    // val_pre fp32 2097152 f
#define QT_OFF   ((size_t)6455296)    // qt bf16 [4][4096][32] = 262144 f
#define KT_OFF   ((size_t)6717440)    // kt bf16 tile-swizzled [4][64 tiles][4KB] = 262144 f
#define VT_OFF   ((size_t)6979584)    // vt bf16 tile-swizzled [4][64 tiles][16KB] = 1048576 f
#define VSC_OFF  ((size_t)8028160)
#define VSH_OFF  ((size_t)8028288)
#define S2_OFF   ((size_t)8028416)
#define SH2_OFF  ((size_t)8028432)
#define PART_OFF ((size_t)8028448)    // bn partials (<=2048 f)
#define ML_OFF   ((size_t)8030496)    // Mpart [2][4][4096] + Lpart [2][4][4096] = 65536 f
// total ~8096032 floats = 32.4 MB

static __device__ __forceinline__ ushort_t f2bf(float x) {
    unsigned int u = __float_as_uint(x);
    unsigned int r = (u + 0x7fffu + ((u >> 16) & 1u)) >> 16;
    return (ushort_t)r;
}

static __device__ __forceinline__ void gload16(const void* g, void* l) {
    __builtin_amdgcn_global_load_lds(
        (const __attribute__((address_space(1))) void*)g,
        (__attribute__((address_space(3))) void*)l, 16, 0, 0);
}

// ---------------- avg pool 3x3 stride 2 with LDS row staging ----------------
__global__ __launch_bounds__(256) void pool2_kernel(const float* __restrict__ src,
                                                    float* __restrict__ dst) {
    int b = blockIdx.x;
    int plane = b >> 4;
    int rg = b & 15;
    __shared__ float rows[9][132];
    const float* sp = src + (size_t)plane * (HH * HH) + (size_t)(rg * 8) * HH;
    #pragma unroll
    for (int j = 0; j < 9; ++j) {
        if (threadIdx.x < HH) rows[j][threadIdx.x] = sp[(size_t)j * HH + threadIdx.x];
    }
    __syncthreads();
    int row = threadIdx.x >> 6, ow = threadIdx.x & 63;
    const float* r0 = rows[2 * row];
    const float* r1 = rows[2 * row + 1];
    const float* r2 = rows[2 * row + 2];
    int x = 2 * ow;
    float sum = r0[x] + r0[x + 1] + r0[x + 2]
              + r1[x] + r1[x + 1] + r1[x + 2]
              + r2[x] + r2[x + 1] + r2[x + 2];
    dst[(size_t)plane * 4096 + (size_t)(rg * 4 + row) * 64 + ow] = sum * (1.0f / 9.0f);
}

// ---------------- query + key 1x1 convs, 4-way c-split; kt written tile-swizzled ----------------
__global__ __launch_bounds__(256) void qk2_kernel(const float* __restrict__ p,
                                                  const float* __restrict__ u,
                                                  const float* __restrict__ Wq,
                                                  const float* __restrict__ Wk,
                                                  ushort_t* __restrict__ qt,
                                                  char* __restrict__ kt_c) {
    int n = blockIdx.x >> 6;
    int mb = blockIdx.x & 63;
    int tid = threadIdx.x;
    int mloc = tid & 63;
    int cs = tid >> 6;
    int m = mb * 64 + mloc;
    int hi = m >> 6, wi = m & 63;

    __shared__ float kacc[4][64][21];

    float coord[8];
    coord[0] = wi * (2.0f / 64.0f) - 1.0f;
    coord[1] = hi * (2.0f / 64.0f) - 1.0f;
    coord[2] = (wi + 1) * (2.0f / 64.0f) - 1.0f;
    coord[3] = (hi + 1) * (2.0f / 64.0f) - 1.0f;
    coord[4] = 0.5f * (coord[0] + coord[2]);
    coord[5] = 0.5f * (coord[1] + coord[3]);
    coord[6] = 1.0f / 64.0f;
    coord[7] = 1.0f / 64.0f;

    // K partial over c in [cs*64, cs*64+64)
    {
        float acc[DD];
        #pragma unroll
        for (int o = 0; o < DD; ++o) acc[o] = 0.0f;
        const float* pc = p + ((size_t)(n * CIN + cs * 64)) * LL + m;
        for (int c0 = 0; c0 < 64; ++c0) {
            float pv = pc[(size_t)c0 * LL];
            const float* wr = Wk + (cs * 64 + c0);
            #pragma unroll
            for (int o = 0; o < DD; ++o) acc[o] = fmaf(pv, wr[o * 264], acc[o]);
        }
        if (cs == 3) {
            #pragma unroll
            for (int j = 0; j < 8; ++j) {
                float cv = coord[j];
                #pragma unroll
                for (int o = 0; o < DD; ++o) acc[o] = fmaf(cv, Wk[o * 264 + CIN + j], acc[o]);
            }
        }
        #pragma unroll
        for (int o = 0; o < DD; ++o) kacc[cs][mloc][o] = acc[o];
    }
    // Q full on wave 0
    if (cs == 0) {
        float acc[DD];
        #pragma unroll
        for (int o = 0; o < DD; ++o) acc[o] = 0.0f;
        for (int cq = 0; cq < CUU; ++cq) {
            float uv = u[((size_t)(n * CUU + cq)) * LL + m];
            #pragma unroll
            for (int o = 0; o < DD; ++o) acc[o] = fmaf(uv, Wq[o * DD + cq], acc[o]);
        }
        #pragma unroll
        for (int j = 0; j < 8; ++j) {
            float cv = coord[j];
            #pragma unroll
            for (int o = 0; o < DD; ++o) acc[o] = fmaf(cv, Wq[o * DD + CUU + j], acc[o]);
        }
        union { short8v v[4]; ushort_t s[32]; } pk;
        #pragma unroll
        for (int o = 0; o < 32; ++o) pk.s[o] = (o < DD) ? f2bf(acc[o]) : (ushort_t)0;
        short8v* qrow = (short8v*)(qt + ((size_t)(n * LL) + m) * 32);
        #pragma unroll
        for (int j = 0; j < 4; ++j) qrow[j] = pk.v[j];
    }
    __syncthreads();
    // reduce 4 partials, write kt tile-swizzled (16B chunk j = cs)
    {
        int j = cs;
        union { short8v v; ushort_t s[8]; } pk;
        #pragma unroll
        for (int i = 0; i < 8; ++i) {
            int o = j * 8 + i;
            float v = 0.0f;
            if (o < DD)
                v = kacc[0][mloc][o] + kacc[1][mloc][o] + kacc[2][mloc][o] + kacc[3][mloc][o];
            pk.s[i] = (o < DD) ? f2bf(v) : (ushort_t)0;
        }
        int byte = ((mloc << 6) | (j << 4)) ^ (((mloc >> 1) & 7) << 4);
        *(short8v*)(kt_c + (size_t)n * 262144 + (size_t)mb * 4096 + byte) = pk.v;
    }
}

// ---------------- val pre-BN GEMM (32-ch blocks) ----------------
__global__ __launch_bounds__(256) void val_gemm_kernel(const float* __restrict__ p,
                                                       const float* __restrict__ Wv,
                                                       float* __restrict__ val_pre) {
    int b = blockIdx.x;
    int n = b >> 6;
    int r = b & 63;
    int cb = r >> 4;
    int mb = r & 15;
    int m = mb * 256 + threadIdx.x;
    int ch0 = cb * 32;

    float acc[32];
    #pragma unroll
    for (int i = 0; i < 32; ++i) acc[i] = 0.0f;

    for (int c = 0; c < CIN; ++c) {
        float pv = p[((size_t)(n * CIN + c)) * LL + m];
        #pragma unroll
        for (int i = 0; i < 32; ++i)
            acc[i] = fmaf(pv, Wv[(ch0 + i) * CIN + c], acc[i]);
    }
    #pragma unroll
    for (int i = 0; i < 32; ++i)
        val_pre[((size_t)(n * CVV + ch0 + i)) * LL + m] = acc[i];
}

// ---------------- BN stats, two-stage ----------------
__global__ __launch_bounds__(256) void bn_partial_kernel(const float* __restrict__ src,
                                                         float* __restrict__ part, int C) {
    int ch = blockIdx.x >> 3;
    int s = blockIdx.x & 7;
    float s1 = 0.0f, s2 = 0.0f;
    #pragma unroll
    for (int k = 0; k < 8; ++k) {
        int e = s * 2048 + k * 256 + threadIdx.x;
        int n = e >> 12;
        int m = e & 4095;
        float v = src[((size_t)(n * C + ch)) * LL + m];
        s1 += v;
        s2 = fmaf(v, v, s2);
    }
    __shared__ float rs[4], rs2[4];
    #pragma unroll
    for (int off = 32; off; off >>= 1) {
        s1 += __shfl_down(s1, off);
        s2 += __shfl_down(s2, off);
    }
    int wid = threadIdx.x >> 6;
    if ((threadIdx.x & 63) == 0) { rs[wid] = s1; rs2[wid] = s2; }
    __syncthreads();
    if (threadIdx.x == 0) {
        part[(size_t)blockIdx.x * 2]     = rs[0] + rs[1] + rs[2] + rs[3];
        part[(size_t)blockIdx.x * 2 + 1] = rs2[0] + rs2[1] + rs2[2] + rs2[3];
    }
}

__global__ __launch_bounds__(128) void bn_finalize_kernel(const float* __restrict__ part,
                                                          const float* __restrict__ g,
                                                          const float* __restrict__ bta,
                                                          float* __restrict__ scale,
                                                          float* __restrict__ shift, int C) {
    int ch = threadIdx.x;
    if (ch >= C) return;
    float s1 = 0.0f, s2 = 0.0f;
    #pragma unroll
    for (int s = 0; s < 8; ++s) {
        s1 += part[(size_t)(ch * 8 + s) * 2];
        s2 += part[(size_t)(ch * 8 + s) * 2 + 1];
    }
    float mean = s1 * (1.0f / (NN * LL));
    float var = s2 * (1.0f / (NN * LL)) - mean * mean;
    float inv = rsqrtf(var + 1e-5f);
    float sc = g[ch] * inv;
    scale[ch] = sc;
    shift[ch] = bta[ch] - mean * sc;
}

// ---------------- apply BN + relu -> bf16 V, tile-swizzled layout ----------------
__global__ __launch_bounds__(256) void bn_apply_kernel(const float* __restrict__ val_pre,
                                                       const float* __restrict__ scale,
                                                       const float* __restrict__ shift,
                                                       char* __restrict__ vt_c) {
    int t = blockIdx.x * 256 + threadIdx.x;   // over NN*CVV*LL, m fastest
    int m = t & 4095;
    int ch = (t >> 12) & 127;
    int n = t >> 19;
    float v = val_pre[((size_t)(n * CVV + ch)) * LL + m];
    v = fmaf(v, scale[ch], shift[ch]);
    ushort_t r = f2bf(fmaxf(v, 0.0f));
    int tile = m >> 6, mloc = m & 63;
    size_t byte = (size_t)n * 1048576 + (size_t)tile * 16384
                + (size_t)(((ch << 7) | (mloc << 1)) ^ ((ch & 7) << 4));
    *(ushort_t*)(vt_c + byte) = r;
}

// ---------------- flash attention: block = 64 q rows x (2048 m half), LDS-staged K/V ----------------
struct PW { union { ushort_t p[16][72]; float ot[16][20]; }; };

__global__ __launch_bounds__(256, 2) void attn_flash_kernel(const ushort_t* __restrict__ qt,
                                                            const char* __restrict__ kt_c,
                                                            const char* __restrict__ vt_c,
                                                            float* __restrict__ Op,
                                                            float* __restrict__ Mp,
                                                            float* __restrict__ Lp) {
    int orig = blockIdx.x;
    int bid = ((orig & 7) << 6) | (orig >> 3);   // XCD-pinned: group (n,s) per XCD
    int qb = bid & 63;
    int sM = (bid >> 6) & 1;
    int n = bid >> 7;
    int tid = threadIdx.x;
    int w = tid >> 6, lane = tid & 63, c = lane & 15, g = lane >> 4;
    int l0w = qb * 64 + w * 16;

    __shared__ __align__(16) ushort_t K_t[2][2048];   // 2 x 4KB (64m x 32k swizzled)
    __shared__ __align__(16) ushort_t V_t[2][8192];   // 2 x 16KB (128ch x 64m swizzled); pass1: K128 store
    __shared__ PW pws[4];

    const char* ktb = kt_c + (size_t)n * 262144;
    const char* vtb = vt_c + (size_t)n * 1048576;
    int tk64 = sM * 32;                               // first 64-m tile index of this half

    short8v qf = *(const short8v*)(qt + (((size_t)n * LL + l0w + c) << 5) + g * 8);
    int vxor = (c & 7) << 4;

    // ================= pass 1: row max over this half =================
    float M[4] = {-3.0e38f, -3.0e38f, -3.0e38f, -3.0e38f};
    {
        const char* src = ktb + (size_t)tk64 * 4096 + w * 2048 + lane * 16;
        gload16(src, (char*)V_t[0] + w * 2048);
        gload16(src + 1024, (char*)V_t[0] + w * 2048 + 1024);
    }
    __syncthreads();
    int buf = 0;
    for (int mt = 0; mt < 16; ++mt) {
        if (mt + 1 < 16) {
            const char* src = ktb + (size_t)(tk64 + (mt + 1) * 2) * 4096 + w * 2048 + lane * 16;
            gload16(src, (char*)V_t[buf ^ 1] + w * 2048);
            gload16(src + 1024, (char*)V_t[buf ^ 1] + w * 2048 + 1024);
        }
        const char* kb = (const char*)V_t[buf];
        #pragma unroll
        for (int t = 0; t < 8; ++t) {
            int krow = t * 16 + c;
            int kby = ((krow << 6) | (g << 4)) ^ (((krow >> 1) & 7) << 4);
            short8v kf = *(const short8v*)(kb + kby);
            f32x4 S = __builtin_amdgcn_mfma_f32_16x16x32_bf16(qf, kf, (f32x4){0.f, 0.f, 0.f, 0.f}, 0, 0, 0);
            #pragma unroll
            for (int r = 0; r < 4; ++r) M[r] = fmaxf(M[r], S[r]);
        }
        __syncthreads();
        buf ^= 1;
    }
    #pragma unroll
    for (int off = 1; off < 16; off <<= 1) {
        #pragma unroll
        for (int r = 0; r < 4; ++r) M[r] = fmaxf(M[r], __shfl_xor(M[r], off));
    }

    // ================= pass 2: P = exp(S-M), O += P V =================
    f32x4 O[8];
    #pragma unroll
    for (int i = 0; i < 8; ++i) O[i] = (f32x4){0.f, 0.f, 0.f, 0.f};
    float Lacc[4] = {0.f, 0.f, 0.f, 0.f};

    {
        const char* ks = ktb + (size_t)tk64 * 4096 + w * 1024 + lane * 16;
        gload16(ks, (char*)K_t[0] + w * 1024);
        const char* vs = vtb + (size_t)tk64 * 16384 + w * 4096 + lane * 16;
        #pragma unroll
        for (int i = 0; i < 4; ++i)
            gload16(vs + i * 1024, (char*)V_t[0] + w * 4096 + i * 1024);
    }
    __syncthreads();
    buf = 0;
    for (int mt = 0; mt < 32; ++mt) {
        if (mt + 1 < 32) {
            const char* ks = ktb + (size_t)(tk64 + mt + 1) * 4096 + w * 1024 + lane * 16;
            gload16(ks, (char*)K_t[buf ^ 1] + w * 1024);
            const char* vs = vtb + (size_t)(tk64 + mt + 1) * 16384 + w * 4096 + lane * 16;
            #pragma unroll
            for (int i = 0; i < 4; ++i)
                gload16(vs + i * 1024, (char*)V_t[buf ^ 1] + w * 4096 + i * 1024);
        }
        // QK
        f32x4 S[4];
        const char* kb = (const char*)K_t[buf];
        #pragma unroll
        for (int t = 0; t < 4; ++t) {
            int krow = t * 16 + c;
            int kby = ((krow << 6) | (g << 4)) ^ (((krow >> 1) & 7) << 4);
            short8v kf = *(const short8v*)(kb + kby);
            S[t] = __builtin_amdgcn_mfma_f32_16x16x32_bf16(qf, kf, (f32x4){0.f, 0.f, 0.f, 0.f}, 0, 0, 0);
        }
        // exp + P tile (wave-private)
        #pragma unroll
        for (int t = 0; t < 4; ++t) {
            #pragma unroll
            for (int r = 0; r < 4; ++r) {
                float pv = __expf(S[t][r] - M[r]);
                Lacc[r] += pv;
                pws[w].p[g * 4 + r][t * 16 + c] = f2bf(pv);
            }
        }
        short8v pa0 = *(const short8v*)&pws[w].p[c][g * 8];
        short8v pa1 = *(const short8v*)&pws[w].p[c][32 + g * 8];
        // PV
        const char* vb = (const char*)V_t[buf];
        #pragma unroll
        for (int ct = 0; ct < 8; ++ct) {
            int row = ct * 16 + c;
            int vby0 = (row << 7) | ((g << 4) ^ vxor);
            int vby1 = (row << 7) | (((1 << 6) | (g << 4)) ^ vxor);
            short8v v0 = *(const short8v*)(vb + vby0);
            short8v v1 = *(const short8v*)(vb + vby1);
            O[ct] = __builtin_amdgcn_mfma_f32_16x16x32_bf16(pa0, v0, O[ct], 0, 0, 0);
            O[ct] = __builtin_amdgcn_mfma_f32_16x16x32_bf16(pa1, v1, O[ct], 0, 0, 0);
        }
        __syncthreads();
        buf ^= 1;
    }
    #pragma unroll
    for (int off = 1; off < 16; off <<= 1) {
        #pragma unroll
        for (int r = 0; r < 4; ++r) Lacc[r] += __shfl_xor(Lacc[r], off);
    }

    // ---- transpose O per 16-ch tile via wave-private LDS, coalesced write ----
    size_t obase = ((size_t)(sM * NN + n) * LL + l0w);
    #pragma unroll
    for (int ct = 0; ct < 8; ++ct) {
        #pragma unroll
        for (int r = 0; r < 4; ++r) pws[w].ot[g * 4 + r][c] = O[ct][r];
        float4 v = *(float4*)&pws[w].ot[c][g * 4];
        *(float4*)&Op[(obase + c) * CVV + ct * 16 + g * 4] = v;
    }
    if (c == 0) {
        #pragma unroll
        for (int r = 0; r < 4; ++r) {
            Mp[sM * (NN * LL) + n * LL + l0w + g * 4 + r] = M[r];
            Lp[sM * (NN * LL) + n * LL + l0w + g * 4 + r] = Lacc[r];
        }
    }
}

// ---------------- merge m-halves + projection ----------------
__global__ __launch_bounds__(256) void proj_merge_kernel(const float* __restrict__ Op,
                                                         const float* __restrict__ Mp,
                                                         const float* __restrict__ Lp,
                                                         const float* __restrict__ Wp,
                                                         float* __restrict__ out_pre) {
    int idx = blockIdx.x * 256 + threadIdx.x;   // over NN*LL
    int n = idx >> 12;
    int l = idx & 4095;
    int nl = n * LL + l;
    float m0 = Mp[nl], m1 = Mp[NN * LL + nl];
    float l0v = Lp[nl], l1v = Lp[NN * LL + nl];
    float Ms = fmaxf(m0, m1);
    float w0 = __expf(m0 - Ms), w1 = __expf(m1 - Ms);
    float inv = 1.0f / (w0 * l0v + w1 * l1v);
    w0 *= inv; w1 *= inv;

    const float4* a4 = (const float4*)(Op + (size_t)nl * CVV);
    const float4* b4 = (const float4*)(Op + ((size_t)(NN * LL) + nl) * CVV);
    float acc[COO];
    #pragma unroll
    for (int o = 0; o < COO; ++o) acc[o] = 0.0f;
    for (int c4 = 0; c4 < CVV / 4; ++c4) {
        float4 a = a4[c4], b = b4[c4];
        float4 v;
        v.x = fmaf(w1, b.x, w0 * a.x);
        v.y = fmaf(w1, b.y, w0 * a.y);
        v.z = fmaf(w1, b.z, w0 * a.z);
        v.w = fmaf(w1, b.w, w0 * a.w);
        #pragma unroll
        for (int o = 0; o < COO; ++o) {
            const float* wr = Wp + o * CVV + c4 * 4;
            acc[o] = fmaf(v.x, wr[0], acc[o]);
            acc[o] = fmaf(v.y, wr[1], acc[o]);
            acc[o] = fmaf(v.z, wr[2], acc[o]);
            acc[o] = fmaf(v.w, wr[3], acc[o]);
        }
    }
    #pragma unroll
    for (int o = 0; o < COO; ++o)
        out_pre[((size_t)(n * COO + o)) * LL + l] = acc[o];
}

// ---------------- BN + relu + bilinear resize (align_corners=True) ----------------
__global__ __launch_bounds__(256) void resize_kernel(const float* __restrict__ out_pre,
                                                     const float* __restrict__ scale,
                                                     const float* __restrict__ shift,
                                                     float* __restrict__ out,
                                                     int total) {
    int idx = blockIdx.x * 256 + threadIdx.x;
    if (idx >= total) return;
    int ow = idx % HH;
    int t = idx / HH;
    int oh = t % HH;
    int t2 = t / HH;
    int o = t2 % COO;
    int n = t2 / COO;

    const float r = 63.0f / 128.0f;
    float y = oh * r;
    float x = ow * r;
    int y0 = (int)y;
    int x0 = (int)x;
    float wy = y - y0;
    float wx = x - x0;
    int y1 = min(y0 + 1, 63);
    int x1 = min(x0 + 1, 63);

    const float* base = out_pre + ((size_t)(n * COO + o)) * LL;
    float sc = scale[o], sh = shift[o];
    float v00 = fmaxf(fmaf(base[y0 * 64 + x0], sc, sh), 0.0f);
    float v01 = fmaxf(fmaf(base[y0 * 64 + x1], sc, sh), 0.0f);
    float v10 = fmaxf(fmaf(base[y1 * 64 + x0], sc, sh), 0.0f);
    float v11 = fmaxf(fmaf(base[y1 * 64 + x1], sc, sh), 0.0f);
    float top = v00 * (1.0f - wx) + v01 * wx;
    float bot = v10 * (1.0f - wx) + v11 * wx;
    out[idx] = top * (1.0f - wy) + bot * wy;
}

extern "C" void kernel_launch(void* const* d_in, const int* in_sizes, int n_in,
                              void* d_out, int out_size, void* d_ws, size_t ws_size,
                              hipStream_t stream) {
    (void)in_sizes; (void)n_in; (void)out_size; (void)ws_size;
    const float* p_fea = (const float*)d_in[0];
    const float* hu    = (const float*)d_in[1];
    const float* Wq    = (const float*)d_in[2];
    const float* Wk    = (const float*)d_in[3];
    const float* Wv    = (const float*)d_in[4];
    const float* g_v   = (const float*)d_in[5];
    const float* b_v   = (const float*)d_in[6];
    const float* Wp    = (const float*)d_in[7];
    const float* g_p   = (const float*)d_in[8];
    const float* b_p   = (const float*)d_in[9];

    float* ws = (float*)d_ws;
    float*    p       = ws + P_OFF;
    float*    u       = ws + U_OFF;
    float*    val_pre = ws + VP_OFF;
    ushort_t* qtb     = (ushort_t*)(ws + QT_OFF);
    char*     ktb     = (char*)(ws + KT_OFF);
    char*     vtb     = (char*)(ws + VT_OFF);
    float*    Opart   = ws + P_OFF;     // alias: p dead after qk2/val_gemm
    float*    out_pre = ws + U_OFF;     // alias: u dead after qk2
    float*    vscale  = ws + VSC_OFF;
    float*    vshift  = ws + VSH_OFF;
    float*    scale2  = ws + S2_OFF;
    float*    shift2  = ws + SH2_OFF;
    float*    part    = ws + PART_OFF;
    float*    Mpart   = ws + ML_OFF;
    float*    Lpart   = ws + ML_OFF + 32768;

    pool2_kernel<<<NN * CIN * 16, 256, 0, stream>>>(p_fea, p);
    pool2_kernel<<<NN * CUU * 16, 256, 0, stream>>>(hu, u);
    qk2_kernel<<<256, 256, 0, stream>>>(p, u, Wq, Wk, qtb, ktb);
    val_gemm_kernel<<<256, 256, 0, stream>>>(p, Wv, val_pre);
    bn_partial_kernel<<<CVV * 8, 256, 0, stream>>>(val_pre, part, CVV);
    bn_finalize_kernel<<<1, 128, 0, stream>>>(part, g_v, b_v, vscale, vshift, CVV);
    bn_apply_kernel<<<(NN * CVV * LL) / 256, 256, 0, stream>>>(val_pre, vscale, vshift, vtb);
    attn_flash_kernel<<<512, 256, 0, stream>>>(qtb, ktb, vtb, Opart, Mpart, Lpart);
    proj_merge_kernel<<<(NN * LL) / 256, 256, 0, stream>>>(Opart, Mpart, Lpart, Wp, out_pre);
    bn_partial_kernel<<<COO * 8, 256, 0, stream>>>(out_pre, part, COO);
    bn_finalize_kernel<<<1, 128, 0, stream>>>(part, g_p, b_p, scale2, shift2, COO);
    {
        int total = NN * COO * HH * HH;
        resize_kernel<<<(total + 255) / 256, 256, 0, stream>>>(out_pre, scale2, shift2,
                                                               (float*)d_out, total);
    }
}

// Round 5
// 155.100 us; speedup vs baseline: 7.7903x; 1.3035x over previous
//
#include <hip/hip_runtime.h>
#include <hip/hip_bf16.h>
#include <cstdint>

// Problem constants
#define NN   4
#define LL   4096      // 64*64
#define DD   18
#define CVV  128
#define CIN  256
#define CUU  10
#define HH   129
#define COO  10

typedef unsigned short ushort_t;
typedef __attribute__((ext_vector_type(8))) short short8v;   // 8 bf16 (4 VGPRs)
typedef __attribute__((ext_vector_type(4))) float f32x4;

// workspace layout (float offsets)
#define P_OFF    ((size_t)0)          // p fp32 4*256*4096 = 4194304 f (later: Opart [2][4][4096][128] = 4194304 f)
#define U_OFF    ((size_t)4194304)    // u fp32 163840 f (later out_pre)
#define VP_OFF   ((size_t)4358144)    // val_pre fp32 2097152 f
#define QT_OFF   ((size_t)6455296)    // qt bf16 [4][4096][32] = 262144 f
#define KT_OFF   ((size_t)6717440)    // kt bf16 tile-swizzled [4][64 tiles][4KB] = 262144 f
#define VT_OFF   ((size_t)6979584)    // vt bf16 tile-swizzled [4][64 tiles][16KB] = 1048576 f
#define VSC_OFF  ((size_t)8028160)
#define VSH_OFF  ((size_t)8028288)
#define S2_OFF   ((size_t)8028416)
#define SH2_OFF  ((size_t)8028432)
#define PART_OFF ((size_t)8028448)    // bn partials (<=2048 f)
#define ML_OFF   ((size_t)8030496)    // Mpart [2][4][4096] + Lpart [2][4][4096] = 65536 f
// total ~8096032 floats = 32.4 MB

static __device__ __forceinline__ ushort_t f2bf(float x) {
    unsigned int u = __float_as_uint(x);
    unsigned int r = (u + 0x7fffu + ((u >> 16) & 1u)) >> 16;
    return (ushort_t)r;
}

static __device__ __forceinline__ void gload16(const void* g, void* l) {
    __builtin_amdgcn_global_load_lds(
        (const __attribute__((address_space(1))) void*)g,
        (__attribute__((address_space(3))) void*)l, 16, 0, 0);
}

// ---------------- avg pool 3x3 stride 2 with LDS row staging ----------------
__global__ __launch_bounds__(256) void pool2_kernel(const float* __restrict__ src,
                                                    float* __restrict__ dst) {
    int b = blockIdx.x;
    int plane = b >> 4;
    int rg = b & 15;
    __shared__ float rows[9][132];
    const float* sp = src + (size_t)plane * (HH * HH) + (size_t)(rg * 8) * HH;
    #pragma unroll
    for (int j = 0; j < 9; ++j) {
        if (threadIdx.x < HH) rows[j][threadIdx.x] = sp[(size_t)j * HH + threadIdx.x];
    }
    __syncthreads();
    int row = threadIdx.x >> 6, ow = threadIdx.x & 63;
    const float* r0 = rows[2 * row];
    const float* r1 = rows[2 * row + 1];
    const float* r2 = rows[2 * row + 2];
    int x = 2 * ow;
    float sum = r0[x] + r0[x + 1] + r0[x + 2]
              + r1[x] + r1[x + 1] + r1[x + 2]
              + r2[x] + r2[x + 1] + r2[x + 2];
    dst[(size_t)plane * 4096 + (size_t)(rg * 4 + row) * 64 + ow] = sum * (1.0f / 9.0f);
}

// ---------------- query + key 1x1 convs, 4-way c-split; kt written tile-swizzled ----------------
__global__ __launch_bounds__(256) void qk2_kernel(const float* __restrict__ p,
                                                  const float* __restrict__ u,
                                                  const float* __restrict__ Wq,
                                                  const float* __restrict__ Wk,
                                                  ushort_t* __restrict__ qt,
                                                  char* __restrict__ kt_c) {
    int n = blockIdx.x >> 6;
    int mb = blockIdx.x & 63;
    int tid = threadIdx.x;
    int mloc = tid & 63;
    int cs = tid >> 6;
    int m = mb * 64 + mloc;
    int hi = m >> 6, wi = m & 63;

    __shared__ float kacc[4][64][21];

    float coord[8];
    coord[0] = wi * (2.0f / 64.0f) - 1.0f;
    coord[1] = hi * (2.0f / 64.0f) - 1.0f;
    coord[2] = (wi + 1) * (2.0f / 64.0f) - 1.0f;
    coord[3] = (hi + 1) * (2.0f / 64.0f) - 1.0f;
    coord[4] = 0.5f * (coord[0] + coord[2]);
    coord[5] = 0.5f * (coord[1] + coord[3]);
    coord[6] = 1.0f / 64.0f;
    coord[7] = 1.0f / 64.0f;

    // K partial over c in [cs*64, cs*64+64)
    {
        float acc[DD];
        #pragma unroll
        for (int o = 0; o < DD; ++o) acc[o] = 0.0f;
        const float* pc = p + ((size_t)(n * CIN + cs * 64)) * LL + m;
        for (int c0 = 0; c0 < 64; ++c0) {
            float pv = pc[(size_t)c0 * LL];
            const float* wr = Wk + (cs * 64 + c0);
            #pragma unroll
            for (int o = 0; o < DD; ++o) acc[o] = fmaf(pv, wr[o * 264], acc[o]);
        }
        if (cs == 3) {
            #pragma unroll
            for (int j = 0; j < 8; ++j) {
                float cv = coord[j];
                #pragma unroll
                for (int o = 0; o < DD; ++o) acc[o] = fmaf(cv, Wk[o * 264 + CIN + j], acc[o]);
            }
        }
        #pragma unroll
        for (int o = 0; o < DD; ++o) kacc[cs][mloc][o] = acc[o];
    }
    // Q full on wave 0
    if (cs == 0) {
        float acc[DD];
        #pragma unroll
        for (int o = 0; o < DD; ++o) acc[o] = 0.0f;
        for (int cq = 0; cq < CUU; ++cq) {
            float uv = u[((size_t)(n * CUU + cq)) * LL + m];
            #pragma unroll
            for (int o = 0; o < DD; ++o) acc[o] = fmaf(uv, Wq[o * DD + cq], acc[o]);
        }
        #pragma unroll
        for (int j = 0; j < 8; ++j) {
            float cv = coord[j];
            #pragma unroll
            for (int o = 0; o < DD; ++o) acc[o] = fmaf(cv, Wq[o * DD + CUU + j], acc[o]);
        }
        union { short8v v[4]; ushort_t s[32]; } pk;
        #pragma unroll
        for (int o = 0; o < 32; ++o) pk.s[o] = (o < DD) ? f2bf(acc[o]) : (ushort_t)0;
        short8v* qrow = (short8v*)(qt + ((size_t)(n * LL) + m) * 32);
        #pragma unroll
        for (int j = 0; j < 4; ++j) qrow[j] = pk.v[j];
    }
    __syncthreads();
    // reduce 4 partials, write kt tile-swizzled (16B chunk j = cs)
    {
        int j = cs;
        union { short8v v; ushort_t s[8]; } pk;
        #pragma unroll
        for (int i = 0; i < 8; ++i) {
            int o = j * 8 + i;
            float v = 0.0f;
            if (o < DD)
                v = kacc[0][mloc][o] + kacc[1][mloc][o] + kacc[2][mloc][o] + kacc[3][mloc][o];
            pk.s[i] = (o < DD) ? f2bf(v) : (ushort_t)0;
        }
        int byte = ((mloc << 6) | (j << 4)) ^ (((mloc >> 1) & 7) << 4);
        *(short8v*)(kt_c + (size_t)n * 262144 + (size_t)mb * 4096 + byte) = pk.v;
    }
}

// ---------------- val pre-BN GEMM: block 32ch x 128m, thread 4ch x 4m, Wv in LDS ----------------
__global__ __launch_bounds__(256, 2) void val_gemm2_kernel(const float* __restrict__ p,
                                                           const float* __restrict__ Wv,
                                                           float* __restrict__ val_pre) {
    int b = blockIdx.x;          // 512 blocks: n(4) x cb(4) x mb(32)
    int n  = b >> 7;
    int cb = (b >> 5) & 3;
    int mb = b & 31;
    int tid = threadIdx.x;
    int cg = tid >> 5;           // 8 groups x 4ch
    int mg = tid & 31;           // 32 groups x 4m
    int ch0 = cb * 32;
    int m0 = mb * 128;

    __shared__ float Wt[256][36];   // transposed Wv tile, padded stride (144B, 16B-aligned)

    // stage Wv[ch0..ch0+32][0..256] -> Wt[c][ch]
    {
        int c4 = tid & 63;          // 64 c-quads
        int chq = tid >> 6;         // 4 groups of 8 ch
        #pragma unroll
        for (int j = 0; j < 8; ++j) {
            int ch = chq * 8 + j;
            float4 v = *(const float4*)&Wv[(size_t)(ch0 + ch) * CIN + c4 * 4];
            Wt[c4 * 4 + 0][ch] = v.x;
            Wt[c4 * 4 + 1][ch] = v.y;
            Wt[c4 * 4 + 2][ch] = v.z;
            Wt[c4 * 4 + 3][ch] = v.w;
        }
    }
    __syncthreads();

    const float* pb = p + (size_t)n * CIN * LL + m0 + mg * 4;
    f32x4 a0 = {0.f,0.f,0.f,0.f}, a1 = {0.f,0.f,0.f,0.f};
    f32x4 a2 = {0.f,0.f,0.f,0.f}, a3 = {0.f,0.f,0.f,0.f};

    #pragma unroll 4
    for (int c = 0; c < CIN; ++c) {
        f32x4 pv = *(const f32x4*)(pb + (size_t)c * LL);
        f32x4 wv = *(const f32x4*)&Wt[c][cg * 4];
        a0 += pv * wv.x;
        a1 += pv * wv.y;
        a2 += pv * wv.z;
        a3 += pv * wv.w;
    }

    size_t out = ((size_t)(n * CVV + ch0 + cg * 4)) * LL + m0 + mg * 4;
    *(f32x4*)&val_pre[out]           = a0;
    *(f32x4*)&val_pre[out + LL]      = a1;
    *(f32x4*)&val_pre[out + 2 * LL]  = a2;
    *(f32x4*)&val_pre[out + 3 * LL]  = a3;
}

// ---------------- BN stats, two-stage ----------------
__global__ __launch_bounds__(256) void bn_partial_kernel(const float* __restrict__ src,
                                                         float* __restrict__ part, int C) {
    int ch = blockIdx.x >> 3;
    int s = blockIdx.x & 7;
    float s1 = 0.0f, s2 = 0.0f;
    #pragma unroll
    for (int k = 0; k < 8; ++k) {
        int e = s * 2048 + k * 256 + threadIdx.x;
        int n = e >> 12;
        int m = e & 4095;
        float v = src[((size_t)(n * C + ch)) * LL + m];
        s1 += v;
        s2 = fmaf(v, v, s2);
    }
    __shared__ float rs[4], rs2[4];
    #pragma unroll
    for (int off = 32; off; off >>= 1) {
        s1 += __shfl_down(s1, off);
        s2 += __shfl_down(s2, off);
    }
    int wid = threadIdx.x >> 6;
    if ((threadIdx.x & 63) == 0) { rs[wid] = s1; rs2[wid] = s2; }
    __syncthreads();
    if (threadIdx.x == 0) {
        part[(size_t)blockIdx.x * 2]     = rs[0] + rs[1] + rs[2] + rs[3];
        part[(size_t)blockIdx.x * 2 + 1] = rs2[0] + rs2[1] + rs2[2] + rs2[3];
    }
}

__global__ __launch_bounds__(128) void bn_finalize_kernel(const float* __restrict__ part,
                                                          const float* __restrict__ g,
                                                          const float* __restrict__ bta,
                                                          float* __restrict__ scale,
                                                          float* __restrict__ shift, int C) {
    int ch = threadIdx.x;
    if (ch >= C) return;
    float s1 = 0.0f, s2 = 0.0f;
    #pragma unroll
    for (int s = 0; s < 8; ++s) {
        s1 += part[(size_t)(ch * 8 + s) * 2];
        s2 += part[(size_t)(ch * 8 + s) * 2 + 1];
    }
    float mean = s1 * (1.0f / (NN * LL));
    float var = s2 * (1.0f / (NN * LL)) - mean * mean;
    float inv = rsqrtf(var + 1e-5f);
    float sc = g[ch] * inv;
    scale[ch] = sc;
    shift[ch] = bta[ch] - mean * sc;
}

// ---------------- apply BN + relu -> bf16 V, tile-swizzled layout ----------------
__global__ __launch_bounds__(256) void bn_apply_kernel(const float* __restrict__ val_pre,
                                                       const float* __restrict__ scale,
                                                       const float* __restrict__ shift,
                                                       char* __restrict__ vt_c) {
    int t = blockIdx.x * 256 + threadIdx.x;   // over NN*CVV*LL, m fastest
    int m = t & 4095;
    int ch = (t >> 12) & 127;
    int n = t >> 19;
    float v = val_pre[((size_t)(n * CVV + ch)) * LL + m];
    v = fmaf(v, scale[ch], shift[ch]);
    ushort_t r = f2bf(fmaxf(v, 0.0f));
    int tile = m >> 6, mloc = m & 63;
    size_t byte = (size_t)n * 1048576 + (size_t)tile * 16384
                + (size_t)(((ch << 7) | (mloc << 1)) ^ ((ch & 7) << 4));
    *(ushort_t*)(vt_c + byte) = r;
}

// ---------------- flash attention: block = 64 q rows x (2048 m half), LDS-staged K/V ----------------
struct PW { union { ushort_t p[16][72]; float ot[16][20]; }; };

__global__ __launch_bounds__(256, 2) void attn_flash_kernel(const ushort_t* __restrict__ qt,
                                                            const char* __restrict__ kt_c,
                                                            const char* __restrict__ vt_c,
                                                            float* __restrict__ Op,
                                                            float* __restrict__ Mp,
                                                            float* __restrict__ Lp) {
    int orig = blockIdx.x;
    int bid = ((orig & 7) << 6) | (orig >> 3);   // XCD-pinned: group (n,s) per XCD
    int qb = bid & 63;
    int sM = (bid >> 6) & 1;
    int n = bid >> 7;
    int tid = threadIdx.x;
    int w = tid >> 6, lane = tid & 63, c = lane & 15, g = lane >> 4;
    int l0w = qb * 64 + w * 16;

    __shared__ __align__(16) ushort_t K_t[2][2048];   // 2 x 4KB (64m x 32k swizzled)
    __shared__ __align__(16) ushort_t V_t[2][8192];   // 2 x 16KB (128ch x 64m swizzled); pass1: K128 store
    __shared__ PW pws[4];

    const char* ktb = kt_c + (size_t)n * 262144;
    const char* vtb = vt_c + (size_t)n * 1048576;
    int tk64 = sM * 32;                               // first 64-m tile index of this half

    short8v qf = *(const short8v*)(qt + (((size_t)n * LL + l0w + c) << 5) + g * 8);
    int vxor = (c & 7) << 4;

    // ================= pass 1: row max over this half =================
    float M[4] = {-3.0e38f, -3.0e38f, -3.0e38f, -3.0e38f};
    {
        const char* src = ktb + (size_t)tk64 * 4096 + w * 2048 + lane * 16;
        gload16(src, (char*)V_t[0] + w * 2048);
        gload16(src + 1024, (char*)V_t[0] + w * 2048 + 1024);
    }
    __syncthreads();
    int buf = 0;
    for (int mt = 0; mt < 16; ++mt) {
        if (mt + 1 < 16) {
            const char* src = ktb + (size_t)(tk64 + (mt + 1) * 2) * 4096 + w * 2048 + lane * 16;
            gload16(src, (char*)V_t[buf ^ 1] + w * 2048);
            gload16(src + 1024, (char*)V_t[buf ^ 1] + w * 2048 + 1024);
        }
        const char* kb = (const char*)V_t[buf];
        #pragma unroll
        for (int t = 0; t < 8; ++t) {
            int krow = t * 16 + c;
            int kby = ((krow << 6) | (g << 4)) ^ (((krow >> 1) & 7) << 4);
            short8v kf = *(const short8v*)(kb + kby);
            f32x4 S = __builtin_amdgcn_mfma_f32_16x16x32_bf16(qf, kf, (f32x4){0.f, 0.f, 0.f, 0.f}, 0, 0, 0);
            #pragma unroll
            for (int r = 0; r < 4; ++r) M[r] = fmaxf(M[r], S[r]);
        }
        __syncthreads();
        buf ^= 1;
    }
    #pragma unroll
    for (int off = 1; off < 16; off <<= 1) {
        #pragma unroll
        for (int r = 0; r < 4; ++r) M[r] = fmaxf(M[r], __shfl_xor(M[r], off));
    }

    // ================= pass 2: P = exp(S-M), O += P V =================
    f32x4 O[8];
    #pragma unroll
    for (int i = 0; i < 8; ++i) O[i] = (f32x4){0.f, 0.f, 0.f, 0.f};
    float Lacc[4] = {0.f, 0.f, 0.f, 0.f};

    {
        const char* ks = ktb + (size_t)tk64 * 4096 + w * 1024 + lane * 16;
        gload16(ks, (char*)K_t[0] + w * 1024);
        const char* vs = vtb + (size_t)tk64 * 16384 + w * 4096 + lane * 16;
        #pragma unroll
        for (int i = 0; i < 4; ++i)
            gload16(vs + i * 1024, (char*)V_t[0] + w * 4096 + i * 1024);
    }
    __syncthreads();
    buf = 0;
    for (int mt = 0; mt < 32; ++mt) {
        if (mt + 1 < 32) {
            const char* ks = ktb + (size_t)(tk64 + mt + 1) * 4096 + w * 1024 + lane * 16;
            gload16(ks, (char*)K_t[buf ^ 1] + w * 1024);
            const char* vs = vtb + (size_t)(tk64 + mt + 1) * 16384 + w * 4096 + lane * 16;
            #pragma unroll
            for (int i = 0; i < 4; ++i)
                gload16(vs + i * 1024, (char*)V_t[buf ^ 1] + w * 4096 + i * 1024);
        }
        // QK
        f32x4 S[4];
        const char* kb = (const char*)K_t[buf];
        #pragma unroll
        for (int t = 0; t < 4; ++t) {
            int krow = t * 16 + c;
            int kby = ((krow << 6) | (g << 4)) ^ (((krow >> 1) & 7) << 4);
            short8v kf = *(const short8v*)(kb + kby);
            S[t] = __builtin_amdgcn_mfma_f32_16x16x32_bf16(qf, kf, (f32x4){0.f, 0.f, 0.f, 0.f}, 0, 0, 0);
        }
        // exp + P tile (wave-private)
        #pragma unroll
        for (int t = 0; t < 4; ++t) {
            #pragma unroll
            for (int r = 0; r < 4; ++r) {
                float pv = __expf(S[t][r] - M[r]);
                Lacc[r] += pv;
                pws[w].p[g * 4 + r][t * 16 + c] = f2bf(pv);
            }
        }
        short8v pa0 = *(const short8v*)&pws[w].p[c][g * 8];
        short8v pa1 = *(const short8v*)&pws[w].p[c][32 + g * 8];
        // PV
        const char* vb = (const char*)V_t[buf];
        #pragma unroll
        for (int ct = 0; ct < 8; ++ct) {
            int row = ct * 16 + c;
            int vby0 = (row << 7) | ((g << 4) ^ vxor);
            int vby1 = (row << 7) | (((1 << 6) | (g << 4)) ^ vxor);
            short8v v0 = *(const short8v*)(vb + vby0);
            short8v v1 = *(const short8v*)(vb + vby1);
            O[ct] = __builtin_amdgcn_mfma_f32_16x16x32_bf16(pa0, v0, O[ct], 0, 0, 0);
            O[ct] = __builtin_amdgcn_mfma_f32_16x16x32_bf16(pa1, v1, O[ct], 0, 0, 0);
        }
        __syncthreads();
        buf ^= 1;
    }
    #pragma unroll
    for (int off = 1; off < 16; off <<= 1) {
        #pragma unroll
        for (int r = 0; r < 4; ++r) Lacc[r] += __shfl_xor(Lacc[r], off);
    }

    // ---- transpose O per 16-ch tile via wave-private LDS, coalesced write ----
    size_t obase = ((size_t)(sM * NN + n) * LL + l0w);
    #pragma unroll
    for (int ct = 0; ct < 8; ++ct) {
        #pragma unroll
        for (int r = 0; r < 4; ++r) pws[w].ot[g * 4 + r][c] = O[ct][r];
        float4 v = *(float4*)&pws[w].ot[c][g * 4];
        *(float4*)&Op[(obase + c) * CVV + ct * 16 + g * 4] = v;
    }
    if (c == 0) {
        #pragma unroll
        for (int r = 0; r < 4; ++r) {
            Mp[sM * (NN * LL) + n * LL + l0w + g * 4 + r] = M[r];
            Lp[sM * (NN * LL) + n * LL + l0w + g * 4 + r] = Lacc[r];
        }
    }
}

// ---------------- merge m-halves + projection ----------------
__global__ __launch_bounds__(256) void proj_merge_kernel(const float* __restrict__ Op,
                                                         const float* __restrict__ Mp,
                                                         const float* __restrict__ Lp,
                                                         const float* __restrict__ Wp,
                                                         float* __restrict__ out_pre) {
    int idx = blockIdx.x * 256 + threadIdx.x;   // over NN*LL
    int n = idx >> 12;
    int l = idx & 4095;
    int nl = n * LL + l;
    float m0 = Mp[nl], m1 = Mp[NN * LL + nl];
    float l0v = Lp[nl], l1v = Lp[NN * LL + nl];
    float Ms = fmaxf(m0, m1);
    float w0 = __expf(m0 - Ms), w1 = __expf(m1 - Ms);
    float inv = 1.0f / (w0 * l0v + w1 * l1v);
    w0 *= inv; w1 *= inv;

    const float4* a4 = (const float4*)(Op + (size_t)nl * CVV);
    const float4* b4 = (const float4*)(Op + ((size_t)(NN * LL) + nl) * CVV);
    float acc[COO];
    #pragma unroll
    for (int o = 0; o < COO; ++o) acc[o] = 0.0f;
    for (int c4 = 0; c4 < CVV / 4; ++c4) {
        float4 a = a4[c4], b = b4[c4];
        float4 v;
        v.x = fmaf(w1, b.x, w0 * a.x);
        v.y = fmaf(w1, b.y, w0 * a.y);
        v.z = fmaf(w1, b.z, w0 * a.z);
        v.w = fmaf(w1, b.w, w0 * a.w);
        #pragma unroll
        for (int o = 0; o < COO; ++o) {
            const float* wr = Wp + o * CVV + c4 * 4;
            acc[o] = fmaf(v.x, wr[0], acc[o]);
            acc[o] = fmaf(v.y, wr[1], acc[o]);
            acc[o] = fmaf(v.z, wr[2], acc[o]);
            acc[o] = fmaf(v.w, wr[3], acc[o]);
        }
    }
    #pragma unroll
    for (int o = 0; o < COO; ++o)
        out_pre[((size_t)(n * COO + o)) * LL + l] = acc[o];
}

// ---------------- BN + relu + bilinear resize (align_corners=True) ----------------
__global__ __launch_bounds__(256) void resize_kernel(const float* __restrict__ out_pre,
                                                     const float* __restrict__ scale,
                                                     const float* __restrict__ shift,
                                                     float* __restrict__ out,
                                                     int total) {
    int idx = blockIdx.x * 256 + threadIdx.x;
    if (idx >= total) return;
    int ow = idx % HH;
    int t = idx / HH;
    int oh = t % HH;
    int t2 = t / HH;
    int o = t2 % COO;
    int n = t2 / COO;

    const float r = 63.0f / 128.0f;
    float y = oh * r;
    float x = ow * r;
    int y0 = (int)y;
    int x0 = (int)x;
    float wy = y - y0;
    float wx = x - x0;
    int y1 = min(y0 + 1, 63);
    int x1 = min(x0 + 1, 63);

    const float* base = out_pre + ((size_t)(n * COO + o)) * LL;
    float sc = scale[o], sh = shift[o];
    float v00 = fmaxf(fmaf(base[y0 * 64 + x0], sc, sh), 0.0f);
    float v01 = fmaxf(fmaf(base[y0 * 64 + x1], sc, sh), 0.0f);
    float v10 = fmaxf(fmaf(base[y1 * 64 + x0], sc, sh), 0.0f);
    float v11 = fmaxf(fmaf(base[y1 * 64 + x1], sc, sh), 0.0f);
    float top = v00 * (1.0f - wx) + v01 * wx;
    float bot = v10 * (1.0f - wx) + v11 * wx;
    out[idx] = top * (1.0f - wy) + bot * wy;
}

extern "C" void kernel_launch(void* const* d_in, const int* in_sizes, int n_in,
                              void* d_out, int out_size, void* d_ws, size_t ws_size,
                              hipStream_t stream) {
    (void)in_sizes; (void)n_in; (void)out_size; (void)ws_size;
    const float* p_fea = (const float*)d_in[0];
    const float* hu    = (const float*)d_in[1];
    const float* Wq    = (const float*)d_in[2];
    const float* Wk    = (const float*)d_in[3];
    const float* Wv    = (const float*)d_in[4];
    const float* g_v   = (const float*)d_in[5];
    const float* b_v   = (const float*)d_in[6];
    const float* Wp    = (const float*)d_in[7];
    const float* g_p   = (const float*)d_in[8];
    const float* b_p   = (const float*)d_in[9];

    float* ws = (float*)d_ws;
    float*    p       = ws + P_OFF;
    float*    u       = ws + U_OFF;
    float*    val_pre = ws + VP_OFF;
    ushort_t* qtb     = (ushort_t*)(ws + QT_OFF);
    char*     ktb     = (char*)(ws + KT_OFF);
    char*     vtb     = (char*)(ws + VT_OFF);
    float*    Opart   = ws + P_OFF;     // alias: p dead after qk2/val_gemm
    float*    out_pre = ws + U_OFF;     // alias: u dead after qk2
    float*    vscale  = ws + VSC_OFF;
    float*    vshift  = ws + VSH_OFF;
    float*    scale2  = ws + S2_OFF;
    float*    shift2  = ws + SH2_OFF;
    float*    part    = ws + PART_OFF;
    float*    Mpart   = ws + ML_OFF;
    float*    Lpart   = ws + ML_OFF + 32768;

    pool2_kernel<<<NN * CIN * 16, 256, 0, stream>>>(p_fea, p);
    pool2_kernel<<<NN * CUU * 16, 256, 0, stream>>>(hu, u);
    qk2_kernel<<<256, 256, 0, stream>>>(p, u, Wq, Wk, qtb, ktb);
    val_gemm2_kernel<<<512, 256, 0, stream>>>(p, Wv, val_pre);
    bn_partial_kernel<<<CVV * 8, 256, 0, stream>>>(val_pre, part, CVV);
    bn_finalize_kernel<<<1, 128, 0, stream>>>(part, g_v, b_v, vscale, vshift, CVV);
    bn_apply_kernel<<<(NN * CVV * LL) / 256, 256, 0, stream>>>(val_pre, vscale, vshift, vtb);
    attn_flash_kernel<<<512, 256, 0, stream>>>(qtb, ktb, vtb, Opart, Mpart, Lpart);
    proj_merge_kernel<<<(NN * LL) / 256, 256, 0, stream>>>(Opart, Mpart, Lpart, Wp, out_pre);
    bn_partial_kernel<<<COO * 8, 256, 0, stream>>>(out_pre, part, COO);
    bn_finalize_kernel<<<1, 128, 0, stream>>>(part, g_p, b_p, scale2, shift2, COO);
    {
        int total = NN * COO * HH * HH;
        resize_kernel<<<(total + 255) / 256, 256, 0, stream>>>(out_pre, scale2, shift2,
                                                               (float*)d_out, total);
    }
}